// Round 5
// baseline (14644.026 us; speedup 1.0000x reference)
//
#include <hip/hip_runtime.h>
#include <cstdint>
#include <cstddef>

typedef __bf16 bf16;
typedef __attribute__((ext_vector_type(4))) __bf16 bf16x4;

__device__ __forceinline__ float sigmf_(float x){ return 1.f/(1.f+expf(-x)); }
__device__ __forceinline__ float eluf_(float x){ return x>0.f ? x : (expf(x)-1.f); }

// ---------------------------------------------------------------------------
// Naive fp32 GEMM: C[m][n] = epi(sum_k A[m][k]*B[k][n]); B natural [K][N].
// grid (N/128, M/4), block 128. EPI: 0 none, 1 +bias, 2 elu(+bias), 4 +bias+resid
// ---------------------------------------------------------------------------
template<int EPI>
__global__ void __launch_bounds__(128)
gemm_nat(const float* __restrict__ A, int lda, const float* __restrict__ B, int ldb,
         float* __restrict__ C, int ldc, int K,
         const float* __restrict__ bias, const float* __restrict__ resid, int ldr)
{
  const int n = blockIdx.x * 128 + threadIdx.x;
  const int m0 = blockIdx.y * 4;
  const float* a = A + (size_t)m0 * lda;
  float s0 = 0.f, s1 = 0.f, s2 = 0.f, s3 = 0.f;
  for (int k = 0; k < K; ++k) {
    float bv = B[(size_t)k * ldb + n];
    s0 = fmaf(a[k], bv, s0);
    s1 = fmaf(a[lda + k], bv, s1);
    s2 = fmaf(a[2 * lda + k], bv, s2);
    s3 = fmaf(a[3 * lda + k], bv, s3);
  }
  float sv[4] = {s0, s1, s2, s3};
  #pragma unroll
  for (int r = 0; r < 4; ++r) {
    float v = sv[r];
    if (EPI == 1) v += bias[n];
    else if (EPI == 2) v = eluf_(v + bias[n]);
    else if (EPI == 4) v += bias[n] + resid[(size_t)(m0 + r) * ldr + n];
    C[(size_t)(m0 + r) * ldc + n] = v;
  }
}

// C[m][n] = sum_k A[m][k]*BT[n][k]  (BT natural [N][K], e.g. torch wih)
__global__ void __launch_bounds__(128)
gemm_bt_nat(const float* __restrict__ A, int lda, const float* __restrict__ BT,
            float* __restrict__ C, int ldc, int K)
{
  const int n = blockIdx.x * 128 + threadIdx.x;
  const int m0 = blockIdx.y * 4;
  const float* a = A + (size_t)m0 * lda;
  const float* bt = BT + (size_t)n * K;
  float s0 = 0.f, s1 = 0.f, s2 = 0.f, s3 = 0.f;
  for (int k = 0; k < K; ++k) {
    float bv = bt[k];
    s0 = fmaf(a[k], bv, s0);
    s1 = fmaf(a[lda + k], bv, s1);
    s2 = fmaf(a[2 * lda + k], bv, s2);
    s3 = fmaf(a[3 * lda + k], bv, s3);
  }
  C[(size_t)m0 * ldc + n] = s0;
  C[(size_t)(m0 + 1) * ldc + n] = s1;
  C[(size_t)(m0 + 2) * ldc + n] = s2;
  C[(size_t)(m0 + 3) * ldc + n] = s3;
}

// ---------------------------------------------------------------------------
// GRN-flat combine: pre = sigmoid(g)*o + skip ; LN(128) ; softmax(128)
// go [1024][256]: cols 0-127 = g (incl bias), 128-255 = o (incl bias)
// Writes sw (fp32) straight into d_out region.
// ---------------------------------------------------------------------------
__global__ void __launch_bounds__(256, 4)
grnflat_sw_kernel(const float* __restrict__ go, const float* __restrict__ skip,
                  const float* __restrict__ lng, const float* __restrict__ lnb,
                  float* __restrict__ sw_out)
{
  const int tid = threadIdx.x;
  const int m = blockIdx.x * 4 + (tid >> 6);
  const int l = tid & 63, c = l * 2;
  float g0 = go[(size_t)m * 256 + c],       g1 = go[(size_t)m * 256 + c + 1];
  float o0 = go[(size_t)m * 256 + 128 + c], o1 = go[(size_t)m * 256 + 128 + c + 1];
  float sk0 = skip[(size_t)m * 128 + c],    sk1 = skip[(size_t)m * 128 + c + 1];
  float p0 = sigmf_(g0) * o0 + sk0;
  float p1 = sigmf_(g1) * o1 + sk1;
  float s = p0 + p1, s2 = p0 * p0 + p1 * p1;
  #pragma unroll
  for (int k = 1; k < 64; k <<= 1) { s += __shfl_xor(s, k, 64); s2 += __shfl_xor(s2, k, 64); }
  float mean = s * (1.f / 128.f);
  float var = s2 * (1.f / 128.f) - mean * mean;
  float rs = rsqrtf(var + 1e-5f);
  float t0 = (p0 - mean) * rs * lng[c] + lnb[c];
  float t1 = (p1 - mean) * rs * lng[c + 1] + lnb[c + 1];
  float mx = fmaxf(t0, t1);
  #pragma unroll
  for (int k = 1; k < 64; k <<= 1) mx = fmaxf(mx, __shfl_xor(mx, k, 64));
  float e0 = expf(t0 - mx), e1 = expf(t1 - mx);
  float se = e0 + e1;
  #pragma unroll
  for (int k = 1; k < 64; k <<= 1) se += __shfl_xor(se, k, 64);
  float inv = 1.f / se;
  float2 wv; wv.x = e0 * inv; wv.y = e1 * inv;
  *(float2*)(sw_out + (size_t)m * 128 + c) = wv;
}

// ---------------------------------------------------------------------------
// Per-variable GRN, naive fp32: block = (feature f, 32-token tile), 256 thr.
// LDS: bufA[256][32] f32 (h1^T then vo^T), bufB[256][32] f32 (h2^T then pre^T).
// Thread tid = output column k (0..255); weights read in natural [h][k] layout.
// ---------------------------------------------------------------------------
__global__ void __launch_bounds__(256, 2)
pervar_naive(const float* __restrict__ x, const float* __restrict__ w1,
             const float* __restrict__ b1, const float* __restrict__ w2,
             const float* __restrict__ b2, const float* __restrict__ wo,
             const float* __restrict__ bo, const float* __restrict__ wg,
             const float* __restrict__ bg, const float* __restrict__ swp,
             const float* __restrict__ sbp, const float* __restrict__ lng,
             const float* __restrict__ lnb, bf16* __restrict__ vbuf, int f0)
{
  __shared__ float bufA[256][32];
  __shared__ float bufB[256][32];
  __shared__ float xr[32];
  const int tid = threadIdx.x;
  const int k = tid;
  const int f = f0 + blockIdx.y;
  const int t0 = blockIdx.x * 32;
  const size_t fb = (size_t)f * 256;
  if (tid < 32) xr[tid] = x[(size_t)(t0 + tid) * 128 + f];
  __syncthreads();
  // h1^T = elu(x*w1+b1)
  {
    float w1k = w1[fb + k], b1k = b1[fb + k];
    #pragma unroll
    for (int m = 0; m < 32; ++m) bufA[k][m] = eluf_(xr[m] * w1k + b1k);
  }
  __syncthreads();
  // h2 = elu(h1 @ w2 + b2) -> bufB
  {
    const float* w2f = w2 + (size_t)f * 65536;
    float acc[32];
    float b2k = b2[fb + k];
    #pragma unroll
    for (int m = 0; m < 32; ++m) acc[m] = b2k;
    for (int h = 0; h < 256; ++h) {
      float wv = w2f[(size_t)h * 256 + k];
      const float4* hr = (const float4*)&bufA[h][0];
      #pragma unroll
      for (int mq = 0; mq < 8; ++mq) {
        float4 hv = hr[mq];
        acc[mq * 4 + 0] = fmaf(hv.x, wv, acc[mq * 4 + 0]);
        acc[mq * 4 + 1] = fmaf(hv.y, wv, acc[mq * 4 + 1]);
        acc[mq * 4 + 2] = fmaf(hv.z, wv, acc[mq * 4 + 2]);
        acc[mq * 4 + 3] = fmaf(hv.w, wv, acc[mq * 4 + 3]);
      }
    }
    __syncthreads();   // all reads of bufA (h1) complete
    #pragma unroll
    for (int m = 0; m < 32; ++m) bufB[k][m] = eluf_(acc[m]);
  }
  __syncthreads();
  // vo = h2 @ wo + bo -> bufA (h1 dead)
  {
    const float* wof = wo + (size_t)f * 65536;
    float acc[32];
    float bok = bo[fb + k];
    #pragma unroll
    for (int m = 0; m < 32; ++m) acc[m] = bok;
    for (int h = 0; h < 256; ++h) {
      float wv = wof[(size_t)h * 256 + k];
      const float4* hr = (const float4*)&bufB[h][0];
      #pragma unroll
      for (int mq = 0; mq < 8; ++mq) {
        float4 hv = hr[mq];
        acc[mq * 4 + 0] = fmaf(hv.x, wv, acc[mq * 4 + 0]);
        acc[mq * 4 + 1] = fmaf(hv.y, wv, acc[mq * 4 + 1]);
        acc[mq * 4 + 2] = fmaf(hv.z, wv, acc[mq * 4 + 2]);
        acc[mq * 4 + 3] = fmaf(hv.w, wv, acc[mq * 4 + 3]);
      }
    }
    #pragma unroll
    for (int m = 0; m < 32; ++m) bufA[k][m] = acc[m];
  }
  __syncthreads();
  // vg = sigmoid(h2 @ wg + bg); pre = vg*vo + x*sw + sb -> bufB (after drain)
  {
    const float* wgf = wg + (size_t)f * 65536;
    float acc[32];
    float bgk = bg[fb + k];
    #pragma unroll
    for (int m = 0; m < 32; ++m) acc[m] = bgk;
    for (int h = 0; h < 256; ++h) {
      float wv = wgf[(size_t)h * 256 + k];
      const float4* hr = (const float4*)&bufB[h][0];
      #pragma unroll
      for (int mq = 0; mq < 8; ++mq) {
        float4 hv = hr[mq];
        acc[mq * 4 + 0] = fmaf(hv.x, wv, acc[mq * 4 + 0]);
        acc[mq * 4 + 1] = fmaf(hv.y, wv, acc[mq * 4 + 1]);
        acc[mq * 4 + 2] = fmaf(hv.z, wv, acc[mq * 4 + 2]);
        acc[mq * 4 + 3] = fmaf(hv.w, wv, acc[mq * 4 + 3]);
      }
    }
    __syncthreads();   // all reads of bufB (h2) complete
    float swk = swp[fb + k], sbk = sbp[fb + k];
    #pragma unroll
    for (int m = 0; m < 32; ++m)
      bufB[k][m] = sigmf_(acc[m]) * bufA[k][m] + xr[m] * swk + sbk;
  }
  __syncthreads();
  // LN over 256 per row m; 8 threads per row
  {
    const int m = tid >> 3, q = tid & 7;
    float s = 0.f, s2 = 0.f;
    #pragma unroll
    for (int i = 0; i < 32; ++i) {
      float v = bufB[q * 32 + i][m];
      s += v; s2 += v * v;
    }
    s += __shfl_xor(s, 1, 64);  s += __shfl_xor(s, 2, 64);  s += __shfl_xor(s, 4, 64);
    s2 += __shfl_xor(s2, 1, 64); s2 += __shfl_xor(s2, 2, 64); s2 += __shfl_xor(s2, 4, 64);
    float mean = s * (1.f / 256.f);
    float var = s2 * (1.f / 256.f) - mean * mean;
    float rs = rsqrtf(var + 1e-5f);
    bf16* dst = vbuf + ((size_t)blockIdx.y * 1024 + t0 + m) * 256 + q * 32;
    #pragma unroll
    for (int i = 0; i < 32; ++i) {
      int c = q * 32 + i;
      dst[i] = (bf16)((bufB[c][m] - mean) * rs * lng[fb + c] + lnb[fb + c]);
    }
  }
}

// ---------------------------------------------------------------------------
// sel reduce: feats[m][h] (+=) sum_f v[f][m][h]*sw[m][f] (+pos_enc at end)
// ---------------------------------------------------------------------------
__global__ void __launch_bounds__(256, 4)
selreduce_kernel(const bf16* __restrict__ vbuf, const float* __restrict__ sw,
                 const float* __restrict__ pos, float* __restrict__ feats,
                 int f0, int FC, int flags)
{
  const int tid = threadIdx.x;
  const int m = blockIdx.x * 4 + (tid >> 6);
  const int hh = (tid & 63) * 4;
  float a0, a1, a2, a3;
  if (flags & 1) { a0 = a1 = a2 = a3 = 0.f; }
  else {
    float4 v = *(const float4*)(feats + (size_t)m * 256 + hh);
    a0 = v.x; a1 = v.y; a2 = v.z; a3 = v.w;
  }
  for (int fi = 0; fi < FC; ++fi) {
    float wgt = sw[(size_t)m * 128 + f0 + fi];
    bf16x4 v = *(const bf16x4*)(vbuf + ((size_t)fi * 1024 + m) * 256 + hh);
    a0 += wgt * (float)v[0]; a1 += wgt * (float)v[1];
    a2 += wgt * (float)v[2]; a3 += wgt * (float)v[3];
  }
  if (flags & 2) {
    float4 p = *(const float4*)(pos + (size_t)(m & 127) * 256 + hh);
    a0 += p.x; a1 += p.y; a2 += p.z; a3 += p.w;
  }
  float4 o; o.x = a0; o.y = a1; o.z = a2; o.w = a3;
  *(float4*)(feats + (size_t)m * 256 + hh) = o;
}

// ---------------------------------------------------------------------------
// LSTM: one block per batch element; both layers sequential; fp32; only
// __syncthreads(). 1024 threads = one gate output each.
// ---------------------------------------------------------------------------
__global__ void __launch_bounds__(1024, 1)
lstm_batch(const float* __restrict__ xpre0,
           const float* __restrict__ whh0f,
           const float* __restrict__ b0a, const float* __restrict__ b0b,
           const float* __restrict__ wih1f, const float* __restrict__ whh1f,
           const float* __restrict__ b1a, const float* __restrict__ b1b,
           float* __restrict__ h0f, float* __restrict__ aseq)
{
  __shared__ float hcur[256];
  __shared__ float gl[1024];
  __shared__ float bs[1024];
  const int g = threadIdx.x;
  const int b = blockIdx.x;
  const float* wr0 = whh0f + (size_t)g * 256;
  const float* wx1 = wih1f + (size_t)g * 256;
  const float* wr1 = whh1f + (size_t)g * 256;

  bs[g] = b0a[g] + b0b[g];
  if (g < 256) hcur[g] = 0.f;
  float c = 0.f;
  __syncthreads();
  for (int t = 0; t < 128; ++t) {
    float s = bs[g] + xpre0[(size_t)(b * 128 + t) * 1024 + g];
    #pragma unroll 8
    for (int k = 0; k < 256; k += 4) {
      float4 wv = *(const float4*)(wr0 + k);
      float4 hv = *(const float4*)(hcur + k);
      s += hv.x * wv.x + hv.y * wv.y + hv.z * wv.z + hv.w * wv.w;
    }
    gl[g] = s;
    __syncthreads();
    if (g < 256) {
      float ii = sigmf_(gl[g]), ff = sigmf_(gl[256 + g]);
      float gz = tanhf(gl[512 + g]), oo = sigmf_(gl[768 + g]);
      c = ff * c + ii * gz;
      float h = oo * tanhf(c);
      hcur[g] = h;
      h0f[(size_t)(b * 128 + t) * 256 + g] = h;
    }
    __syncthreads();
  }
  bs[g] = b1a[g] + b1b[g];
  if (g < 256) hcur[g] = 0.f;
  c = 0.f;
  __syncthreads();
  for (int t = 0; t < 128; ++t) {
    const float* x0 = h0f + (size_t)(b * 128 + t) * 256;
    float s = bs[g];
    #pragma unroll 4
    for (int k = 0; k < 256; k += 4) {
      float4 wxv = *(const float4*)(wx1 + k);
      float4 wvv = *(const float4*)(wr1 + k);
      float4 xv = *(const float4*)(x0 + k);
      float4 hv = *(const float4*)(hcur + k);
      s += xv.x * wxv.x + xv.y * wxv.y + xv.z * wxv.z + xv.w * wxv.w;
      s += hv.x * wvv.x + hv.y * wvv.y + hv.z * wvv.z + hv.w * wvv.w;
    }
    gl[g] = s;
    __syncthreads();
    if (g < 256) {
      float ii = sigmf_(gl[g]), ff = sigmf_(gl[256 + g]);
      float gz = tanhf(gl[512 + g]), oo = sigmf_(gl[768 + g]);
      c = ff * c + ii * gz;
      float h = oo * tanhf(c);
      hcur[g] = h;
      aseq[(size_t)(b * 128 + t) * 256 + g] = h;
    }
    __syncthreads();
  }
}

// ---------------------------------------------------------------------------
// Attention core per (b,h): scores->softmax->ctx (fp32, logits tiny).
// ---------------------------------------------------------------------------
__global__ void __launch_bounds__(256, 2)
attn_kernel(const float* __restrict__ qkv, float* __restrict__ ctxo)
{
  __shared__ float Kb[128][40];
  __shared__ float Vb[128][40];
  const int tid = threadIdx.x;
  const int b = blockIdx.x >> 3, h = blockIdx.x & 7;
  const int s = tid >> 1, half = tid & 1;
  {
    const float* kr = qkv + ((size_t)(b * 128 + s)) * 768 + 256 + h * 32 + half * 16;
    #pragma unroll
    for (int i = 0; i < 4; ++i) {
      *(float4*)&Kb[s][half * 16 + i * 4] = *(const float4*)(kr + i * 4);
      *(float4*)&Vb[s][half * 16 + i * 4] = *(const float4*)(kr + 256 + i * 4);
    }
  }
  float q[32];
  {
    const float* qr = qkv + ((size_t)(b * 128 + s)) * 768 + h * 32;
    #pragma unroll
    for (int i = 0; i < 8; ++i) {
      float4 v = *(const float4*)(qr + i * 4);
      q[i * 4 + 0] = v.x; q[i * 4 + 1] = v.y; q[i * 4 + 2] = v.z; q[i * 4 + 3] = v.w;
    }
  }
  __syncthreads();
  const float scale = 0.17677669529663687f;  // 1/sqrt(32)
  float se = 0.f;
  float ca[32];
  #pragma unroll
  for (int i = 0; i < 32; ++i) ca[i] = 0.f;
  for (int c0 = 0; c0 < 64; ++c0) {
    int c = half * 64 + c0;
    float d = 0.f;
    #pragma unroll
    for (int i = 0; i < 32; ++i) d += q[i] * Kb[c][i];
    float e = expf(d * scale);
    se += e;
    #pragma unroll
    for (int i = 0; i < 32; ++i) ca[i] += e * Vb[c][i];
  }
  se += __shfl_xor(se, 1, 64);
  #pragma unroll
  for (int i = 0; i < 32; ++i) ca[i] += __shfl_xor(ca[i], 1, 64);
  if (half == 0) {
    float inv = 1.f / se;
    float* outp = ctxo + ((size_t)(b * 128 + s)) * 256 + h * 32;
    #pragma unroll
    for (int i = 0; i < 32; i += 4) {
      float4 v; v.x = ca[i] * inv; v.y = ca[i + 1] * inv; v.z = ca[i + 2] * inv; v.w = ca[i + 3] * inv;
      *(float4*)(outp + i) = v;
    }
  }
}

// LN over 256 cols; optional fp32 mirror (final layer -> d_out 'a')
__global__ void __launch_bounds__(256, 4)
ln_kernel(const float* __restrict__ in, const float* __restrict__ g,
          const float* __restrict__ bta, float* __restrict__ out,
          float* __restrict__ mirror)
{
  const int tid = threadIdx.x;
  const int m = blockIdx.x * 4 + (tid >> 6);
  const int l = tid & 63;
  float4 v = *(const float4*)(in + (size_t)m * 256 + l * 4);
  float s = v.x + v.y + v.z + v.w;
  float s2 = v.x * v.x + v.y * v.y + v.z * v.z + v.w * v.w;
  #pragma unroll
  for (int k = 1; k < 64; k <<= 1) { s += __shfl_xor(s, k, 64); s2 += __shfl_xor(s2, k, 64); }
  float mean = s * (1.f / 256.f);
  float var = s2 * (1.f / 256.f) - mean * mean;
  float rs = rsqrtf(var + 1e-5f);
  float4 gg = *(const float4*)(g + l * 4);
  float4 bb = *(const float4*)(bta + l * 4);
  float4 o;
  o.x = (v.x - mean) * rs * gg.x + bb.x;
  o.y = (v.y - mean) * rs * gg.y + bb.y;
  o.z = (v.z - mean) * rs * gg.z + bb.z;
  o.w = (v.w - mean) * rs * gg.w + bb.w;
  *(float4*)(out + (size_t)m * 256 + l * 4) = o;
  if (mirror) *(float4*)(mirror + (size_t)m * 256 + l * 4) = o;
}

__global__ void __launch_bounds__(256)
gctx_kernel(const float* __restrict__ a, float* __restrict__ g)
{
  int b = blockIdx.x, hh = threadIdx.x;
  float s = 0.f;
  for (int ss = 0; ss < 128; ++ss) s += a[((size_t)b * 128 + ss) * 256 + hh];
  g[b * 256 + hh] = s * (1.f / 128.f);
}

__global__ void __launch_bounds__(256, 1)
head_kernel(const float* __restrict__ g, const float* __restrict__ w1,
            const float* __restrict__ b1, const float* __restrict__ w2,
            const float* __restrict__ b2, const float* __restrict__ qw,
            const float* __restrict__ qb, float* __restrict__ dout)
{
  __shared__ float hid[8][128];
  const int tid = threadIdx.x;
  for (int o = tid; o < 1024; o += 256) {
    int b = o >> 7, j = o & 127;
    float s = b1[j];
    for (int k = 0; k < 256; ++k) s += g[b * 256 + k] * w1[(size_t)k * 128 + j];
    hid[b][j] = s > 0.f ? s : 0.f;
  }
  __syncthreads();
  if (tid < 192) {
    int b = tid / 24, j = tid - b * 24;
    float s = b2[j];
    for (int k = 0; k < 128; ++k) s += hid[b][k] * w2[(size_t)k * 24 + j];
    dout[b * 24 + j] = s;
  }
  for (int o = tid; o < 576; o += 256) {
    int qi = o / 192, rr = o - qi * 192, b = rr / 24, j = rr - b * 24;
    float s = qb[qi * 24 + j];
    for (int k = 0; k < 256; ++k) s += g[b * 256 + k] * qw[((size_t)qi * 256 + k) * 24 + j];
    dout[192 + o] = s;
  }
}

// ---------------------------------------------------------------------------
extern "C" void kernel_launch(void* const* d_in, const int* in_sizes, int n_in,
                              void* d_out, int out_size, void* d_ws, size_t ws_size,
                              hipStream_t stream)
{
  (void)in_sizes; (void)n_in; (void)out_size;
  auto F = [&](int i) { return (const float*)d_in[i]; };
  char* ws = (char*)d_ws;
  size_t o = 0;
  auto alloc = [&](size_t b) { size_t r = o; o = (o + b + 255) & ~(size_t)255; return r; };

  size_t h_o    = alloc((size_t)1024 * 256 * 4);
  size_t h2_o   = alloc((size_t)1024 * 256 * 4);
  size_t go_o   = alloc((size_t)1024 * 256 * 4);
  size_t skip_o = alloc((size_t)1024 * 128 * 4);
  size_t feat_o = alloc((size_t)1024 * 256 * 4);
  size_t xpre_o = alloc((size_t)1024 * 1024 * 4);
  size_t qkv_o  = alloc((size_t)1024 * 768 * 4);
  size_t ctx_o  = alloc((size_t)1024 * 256 * 4);
  size_t pre_o  = alloc((size_t)1024 * 256 * 4);
  size_t aA_o   = alloc((size_t)1024 * 256 * 4);
  size_t aB_o   = alloc((size_t)1024 * 256 * 4);
  size_t gctx_o = alloc(8 * 256 * 4);
  size_t h0f_o  = alloc((size_t)1024 * 256 * 4);
  size_t aseq_o = alloc((size_t)1024 * 256 * 4);
  int FC = 32;
  while (FC > 4 && o + (size_t)FC * 1024 * 256 * 2 > ws_size) FC >>= 1;
  size_t vb_o = alloc((size_t)FC * 1024 * 256 * 2);
  if (o > ws_size) return;

  float* hp    = (float*)(ws + h_o);
  float* h2p   = (float*)(ws + h2_o);
  float* gop   = (float*)(ws + go_o);
  float* skipp = (float*)(ws + skip_o);
  float* featp = (float*)(ws + feat_o);
  float* xprep = (float*)(ws + xpre_o);
  float* qkvp  = (float*)(ws + qkv_o);
  float* ctxp  = (float*)(ws + ctx_o);
  float* prep  = (float*)(ws + pre_o);
  float* aAp   = (float*)(ws + aA_o);
  float* aBp   = (float*)(ws + aB_o);
  float* gctxp = (float*)(ws + gctx_o);
  float* h0fp  = (float*)(ws + h0f_o);
  float* aseqp = (float*)(ws + aseq_o);
  bf16* vbp    = (bf16*)(ws + vb_o);

  // d_out is FP32 (reference outputs are float32).
  // Layout (fp32 elements): pf@0[192], q10@192, q50@384, q90@576, sw@768[131072], a@131840[262144]
  float* outp  = (float*)d_out;
  float* sw_do = outp + 768;
  float* a_do  = outp + 131840;

  // ---- flattened GRN -> variable selection weights ----
  gemm_nat<2><<<dim3(2, 256), 128, 0, stream>>>(F(0), 128, F(1), 256, hp, 256, 128, F(2), nullptr, 0);
  gemm_nat<2><<<dim3(2, 256), 128, 0, stream>>>(hp, 256, F(3), 256, h2p, 256, 256, F(4), nullptr, 0);
  gemm_nat<1><<<dim3(1, 256), 128, 0, stream>>>(h2p, 256, F(7), 128, gop, 256, 256, F(8), nullptr, 0);
  gemm_nat<1><<<dim3(1, 256), 128, 0, stream>>>(h2p, 256, F(5), 128, gop + 128, 256, 256, F(6), nullptr, 0);
  gemm_nat<1><<<dim3(1, 256), 128, 0, stream>>>(F(0), 128, F(9), 128, skipp, 128, 128, F(10), nullptr, 0);
  grnflat_sw_kernel<<<256, 256, 0, stream>>>(gop, skipp, F(11), F(12), sw_do);

  // ---- per-variable GRNs (chunked over features) ----
  int chunks = 128 / FC;
  for (int c = 0; c < chunks; ++c) {
    pervar_naive<<<dim3(32, FC), 256, 0, stream>>>(
        F(0), F(13), F(14), F(15), F(16), F(17), F(18), F(19), F(20), F(21), F(22),
        F(23), F(24), vbp, c * FC);
    selreduce_kernel<<<256, 256, 0, stream>>>(
        vbp, sw_do, F(25), featp, c * FC, FC,
        (c == 0 ? 1 : 0) | (c == chunks - 1 ? 2 : 0));
  }

  // ---- LSTM ----
  gemm_bt_nat<<<dim3(8, 256), 128, 0, stream>>>(featp, 256, F(26), xprep, 1024, 256);
  lstm_batch<<<8, 1024, 0, stream>>>(xprep, F(27), F(28), F(29), F(30), F(31),
                                     F(32), F(33), h0fp, aseqp);

  // ---- attention layers ----
  const float* ain = aseqp;
  float* louts[4] = {aAp, aBp, aAp, aBp};
  for (int l = 0; l < 4; ++l) {
    const float* wq = F(34) + (size_t)l * 65536;
    const float* wk = F(35) + (size_t)l * 65536;
    const float* wv = F(36) + (size_t)l * 65536;
    const float* wo = F(37) + (size_t)l * 65536;
    gemm_nat<0><<<dim3(2, 256), 128, 0, stream>>>(ain, 256, wq, 256, qkvp,       768, 256, nullptr, nullptr, 0);
    gemm_nat<0><<<dim3(2, 256), 128, 0, stream>>>(ain, 256, wk, 256, qkvp + 256, 768, 256, nullptr, nullptr, 0);
    gemm_nat<0><<<dim3(2, 256), 128, 0, stream>>>(ain, 256, wv, 256, qkvp + 512, 768, 256, nullptr, nullptr, 0);
    attn_kernel<<<64, 256, 0, stream>>>(qkvp, ctxp);
    gemm_nat<4><<<dim3(2, 256), 128, 0, stream>>>(ctxp, 256, wo, 256, prep, 256, 256,
                                                  F(38) + (size_t)l * 256, ain, 256);
    ln_kernel<<<256, 256, 0, stream>>>(prep, F(39) + (size_t)l * 256, F(40) + (size_t)l * 256,
                                       louts[l], l == 3 ? a_do : (float*)nullptr);
    ain = louts[l];
  }

  // ---- heads ----
  gctx_kernel<<<8, 256, 0, stream>>>(aBp, gctxp);
  head_kernel<<<1, 256, 0, stream>>>(gctxp, F(41), F(42), F(43), F(44), F(45), F(46), outp);
}

// Round 6
// 3401.829 us; speedup vs baseline: 4.3048x; 4.3048x over previous
//
#include <hip/hip_runtime.h>
#include <cstdint>
#include <cstddef>

typedef __bf16 bf16;
typedef __attribute__((ext_vector_type(4))) __bf16 bf16x4;
typedef __attribute__((ext_vector_type(8))) __bf16 bf16x8;
typedef __attribute__((ext_vector_type(4))) float floatx4;

#define MFMA16(a,b,c) __builtin_amdgcn_mfma_f32_16x16x32_bf16(a,b,c,0,0,0)

__device__ __forceinline__ float sigmf_(float x){ return 1.f/(1.f+expf(-x)); }
__device__ __forceinline__ float eluf_(float x){ return x>0.f ? x : (expf(x)-1.f); }

// ---------------------------------------------------------------------------
// Naive fp32 GEMM: C[m][n] = epi(sum_k A[m][k]*B[k][n]); B natural [K][N].
// grid (N/128, M/4), block 128. EPI: 0 none, 1 +bias, 2 elu(+bias), 4 +bias+resid
// ---------------------------------------------------------------------------
template<int EPI>
__global__ void __launch_bounds__(128)
gemm_nat(const float* __restrict__ A, int lda, const float* __restrict__ B, int ldb,
         float* __restrict__ C, int ldc, int K,
         const float* __restrict__ bias, const float* __restrict__ resid, int ldr)
{
  const int n = blockIdx.x * 128 + threadIdx.x;
  const int m0 = blockIdx.y * 4;
  const float* a = A + (size_t)m0 * lda;
  float s0 = 0.f, s1 = 0.f, s2 = 0.f, s3 = 0.f;
  for (int k = 0; k < K; ++k) {
    float bv = B[(size_t)k * ldb + n];
    s0 = fmaf(a[k], bv, s0);
    s1 = fmaf(a[lda + k], bv, s1);
    s2 = fmaf(a[2 * lda + k], bv, s2);
    s3 = fmaf(a[3 * lda + k], bv, s3);
  }
  float sv[4] = {s0, s1, s2, s3};
  #pragma unroll
  for (int r = 0; r < 4; ++r) {
    float v = sv[r];
    if (EPI == 1) v += bias[n];
    else if (EPI == 2) v = eluf_(v + bias[n]);
    else if (EPI == 4) v += bias[n] + resid[(size_t)(m0 + r) * ldr + n];
    C[(size_t)(m0 + r) * ldc + n] = v;
  }
}

// C[m][n] = sum_k A[m][k]*BT[n][k]  (BT natural [N][K], e.g. torch wih)
__global__ void __launch_bounds__(128)
gemm_bt_nat(const float* __restrict__ A, int lda, const float* __restrict__ BT,
            float* __restrict__ C, int ldc, int K)
{
  const int n = blockIdx.x * 128 + threadIdx.x;
  const int m0 = blockIdx.y * 4;
  const float* a = A + (size_t)m0 * lda;
  const float* bt = BT + (size_t)n * K;
  float s0 = 0.f, s1 = 0.f, s2 = 0.f, s3 = 0.f;
  for (int k = 0; k < K; ++k) {
    float bv = bt[k];
    s0 = fmaf(a[k], bv, s0);
    s1 = fmaf(a[lda + k], bv, s1);
    s2 = fmaf(a[2 * lda + k], bv, s2);
    s3 = fmaf(a[3 * lda + k], bv, s3);
  }
  C[(size_t)m0 * ldc + n] = s0;
  C[(size_t)(m0 + 1) * ldc + n] = s1;
  C[(size_t)(m0 + 2) * ldc + n] = s2;
  C[(size_t)(m0 + 3) * ldc + n] = s3;
}

// fp32 -> bf16 convert of 4 lstm weight matrices (each 262144 elems)
__global__ void __launch_bounds__(256)
cvt4_kernel(const float* __restrict__ s0, const float* __restrict__ s1,
            const float* __restrict__ s2, const float* __restrict__ s3,
            bf16* __restrict__ dst)
{
  size_t i = ((size_t)blockIdx.x * 256 + threadIdx.x) * 4;
  int mat = (int)(i >> 18);
  const float* s = (mat == 0) ? s0 : (mat == 1) ? s1 : (mat == 2) ? s2 : s3;
  float4 v = *(const float4*)(s + (i & 262143));
  bf16x4 o; o[0]=(bf16)v.x; o[1]=(bf16)v.y; o[2]=(bf16)v.z; o[3]=(bf16)v.w;
  *(bf16x4*)(dst + i) = o;
}

// ---------------------------------------------------------------------------
// GRN-flat combine: pre = sigmoid(g)*o + skip ; LN(128) ; softmax(128)
// ---------------------------------------------------------------------------
__global__ void __launch_bounds__(256, 4)
grnflat_sw_kernel(const float* __restrict__ go, const float* __restrict__ skip,
                  const float* __restrict__ lng, const float* __restrict__ lnb,
                  float* __restrict__ sw_out)
{
  const int tid = threadIdx.x;
  const int m = blockIdx.x * 4 + (tid >> 6);
  const int l = tid & 63, c = l * 2;
  float g0 = go[(size_t)m * 256 + c],       g1 = go[(size_t)m * 256 + c + 1];
  float o0 = go[(size_t)m * 256 + 128 + c], o1 = go[(size_t)m * 256 + 128 + c + 1];
  float sk0 = skip[(size_t)m * 128 + c],    sk1 = skip[(size_t)m * 128 + c + 1];
  float p0 = sigmf_(g0) * o0 + sk0;
  float p1 = sigmf_(g1) * o1 + sk1;
  float s = p0 + p1, s2 = p0 * p0 + p1 * p1;
  #pragma unroll
  for (int k = 1; k < 64; k <<= 1) { s += __shfl_xor(s, k, 64); s2 += __shfl_xor(s2, k, 64); }
  float mean = s * (1.f / 128.f);
  float var = s2 * (1.f / 128.f) - mean * mean;
  float rs = rsqrtf(var + 1e-5f);
  float t0 = (p0 - mean) * rs * lng[c] + lnb[c];
  float t1 = (p1 - mean) * rs * lng[c + 1] + lnb[c + 1];
  float mx = fmaxf(t0, t1);
  #pragma unroll
  for (int k = 1; k < 64; k <<= 1) mx = fmaxf(mx, __shfl_xor(mx, k, 64));
  float e0 = expf(t0 - mx), e1 = expf(t1 - mx);
  float se = e0 + e1;
  #pragma unroll
  for (int k = 1; k < 64; k <<= 1) se += __shfl_xor(se, k, 64);
  float inv = 1.f / se;
  float2 wv; wv.x = e0 * inv; wv.y = e1 * inv;
  *(float2*)(sw_out + (size_t)m * 128 + c) = wv;
}

// ---------------------------------------------------------------------------
// Per-variable GRN, naive fp32: block = (feature f, 32-token tile), 256 thr.
// ---------------------------------------------------------------------------
__global__ void __launch_bounds__(256, 2)
pervar_naive(const float* __restrict__ x, const float* __restrict__ w1,
             const float* __restrict__ b1, const float* __restrict__ w2,
             const float* __restrict__ b2, const float* __restrict__ wo,
             const float* __restrict__ bo, const float* __restrict__ wg,
             const float* __restrict__ bg, const float* __restrict__ swp,
             const float* __restrict__ sbp, const float* __restrict__ lng,
             const float* __restrict__ lnb, bf16* __restrict__ vbuf, int f0)
{
  __shared__ float bufA[256][32];
  __shared__ float bufB[256][32];
  __shared__ float xr[32];
  const int tid = threadIdx.x;
  const int k = tid;
  const int f = f0 + blockIdx.y;
  const int t0 = blockIdx.x * 32;
  const size_t fb = (size_t)f * 256;
  if (tid < 32) xr[tid] = x[(size_t)(t0 + tid) * 128 + f];
  __syncthreads();
  {
    float w1k = w1[fb + k], b1k = b1[fb + k];
    #pragma unroll
    for (int m = 0; m < 32; ++m) bufA[k][m] = eluf_(xr[m] * w1k + b1k);
  }
  __syncthreads();
  {
    const float* w2f = w2 + (size_t)f * 65536;
    float acc[32];
    float b2k = b2[fb + k];
    #pragma unroll
    for (int m = 0; m < 32; ++m) acc[m] = b2k;
    for (int h = 0; h < 256; ++h) {
      float wv = w2f[(size_t)h * 256 + k];
      const float4* hr = (const float4*)&bufA[h][0];
      #pragma unroll
      for (int mq = 0; mq < 8; ++mq) {
        float4 hv = hr[mq];
        acc[mq * 4 + 0] = fmaf(hv.x, wv, acc[mq * 4 + 0]);
        acc[mq * 4 + 1] = fmaf(hv.y, wv, acc[mq * 4 + 1]);
        acc[mq * 4 + 2] = fmaf(hv.z, wv, acc[mq * 4 + 2]);
        acc[mq * 4 + 3] = fmaf(hv.w, wv, acc[mq * 4 + 3]);
      }
    }
    __syncthreads();
    #pragma unroll
    for (int m = 0; m < 32; ++m) bufB[k][m] = eluf_(acc[m]);
  }
  __syncthreads();
  {
    const float* wof = wo + (size_t)f * 65536;
    float acc[32];
    float bok = bo[fb + k];
    #pragma unroll
    for (int m = 0; m < 32; ++m) acc[m] = bok;
    for (int h = 0; h < 256; ++h) {
      float wv = wof[(size_t)h * 256 + k];
      const float4* hr = (const float4*)&bufB[h][0];
      #pragma unroll
      for (int mq = 0; mq < 8; ++mq) {
        float4 hv = hr[mq];
        acc[mq * 4 + 0] = fmaf(hv.x, wv, acc[mq * 4 + 0]);
        acc[mq * 4 + 1] = fmaf(hv.y, wv, acc[mq * 4 + 1]);
        acc[mq * 4 + 2] = fmaf(hv.z, wv, acc[mq * 4 + 2]);
        acc[mq * 4 + 3] = fmaf(hv.w, wv, acc[mq * 4 + 3]);
      }
    }
    #pragma unroll
    for (int m = 0; m < 32; ++m) bufA[k][m] = acc[m];
  }
  __syncthreads();
  {
    const float* wgf = wg + (size_t)f * 65536;
    float acc[32];
    float bgk = bg[fb + k];
    #pragma unroll
    for (int m = 0; m < 32; ++m) acc[m] = bgk;
    for (int h = 0; h < 256; ++h) {
      float wv = wgf[(size_t)h * 256 + k];
      const float4* hr = (const float4*)&bufB[h][0];
      #pragma unroll
      for (int mq = 0; mq < 8; ++mq) {
        float4 hv = hr[mq];
        acc[mq * 4 + 0] = fmaf(hv.x, wv, acc[mq * 4 + 0]);
        acc[mq * 4 + 1] = fmaf(hv.y, wv, acc[mq * 4 + 1]);
        acc[mq * 4 + 2] = fmaf(hv.z, wv, acc[mq * 4 + 2]);
        acc[mq * 4 + 3] = fmaf(hv.w, wv, acc[mq * 4 + 3]);
      }
    }
    __syncthreads();
    float swk = swp[fb + k], sbk = sbp[fb + k];
    #pragma unroll
    for (int m = 0; m < 32; ++m)
      bufB[k][m] = sigmf_(acc[m]) * bufA[k][m] + xr[m] * swk + sbk;
  }
  __syncthreads();
  {
    const int m = tid >> 3, q = tid & 7;
    float s = 0.f, s2 = 0.f;
    #pragma unroll
    for (int i = 0; i < 32; ++i) {
      float v = bufB[q * 32 + i][m];
      s += v; s2 += v * v;
    }
    s += __shfl_xor(s, 1, 64);  s += __shfl_xor(s, 2, 64);  s += __shfl_xor(s, 4, 64);
    s2 += __shfl_xor(s2, 1, 64); s2 += __shfl_xor(s2, 2, 64); s2 += __shfl_xor(s2, 4, 64);
    float mean = s * (1.f / 256.f);
    float var = s2 * (1.f / 256.f) - mean * mean;
    float rs = rsqrtf(var + 1e-5f);
    bf16* dst = vbuf + ((size_t)blockIdx.y * 1024 + t0 + m) * 256 + q * 32;
    #pragma unroll
    for (int i = 0; i < 32; ++i) {
      int c = q * 32 + i;
      dst[i] = (bf16)((bufB[c][m] - mean) * rs * lng[fb + c] + lnb[fb + c]);
    }
  }
}

// ---------------------------------------------------------------------------
// sel reduce: feats[m][h] (+=) sum_f v[f][m][h]*sw[m][f] (+pos_enc at end)
// ---------------------------------------------------------------------------
__global__ void __launch_bounds__(256, 4)
selreduce_kernel(const bf16* __restrict__ vbuf, const float* __restrict__ sw,
                 const float* __restrict__ pos, float* __restrict__ feats,
                 int f0, int FC, int flags)
{
  const int tid = threadIdx.x;
  const int m = blockIdx.x * 4 + (tid >> 6);
  const int hh = (tid & 63) * 4;
  float a0, a1, a2, a3;
  if (flags & 1) { a0 = a1 = a2 = a3 = 0.f; }
  else {
    float4 v = *(const float4*)(feats + (size_t)m * 256 + hh);
    a0 = v.x; a1 = v.y; a2 = v.z; a3 = v.w;
  }
  for (int fi = 0; fi < FC; ++fi) {
    float wgt = sw[(size_t)m * 128 + f0 + fi];
    bf16x4 v = *(const bf16x4*)(vbuf + ((size_t)fi * 1024 + m) * 256 + hh);
    a0 += wgt * (float)v[0]; a1 += wgt * (float)v[1];
    a2 += wgt * (float)v[2]; a3 += wgt * (float)v[3];
  }
  if (flags & 2) {
    float4 p = *(const float4*)(pos + (size_t)(m & 127) * 256 + hh);
    a0 += p.x; a1 += p.y; a2 += p.z; a3 += p.w;
  }
  float4 o; o.x = a0; o.y = a1; o.z = a2; o.w = a3;
  *(float4*)(feats + (size_t)m * 256 + hh) = o;
}

// ---------------------------------------------------------------------------
// LSTM v3: 32 blocks x 256 thr. Block = (layer, 16-unit group). Weight
// fragments VGPR-resident; MFMA 16x16x32 over all 8 batches per step;
// per-step device-scope barrier (release atomicAdd / acquire poll).
// h seq layout: [t][16(batch,pad)][256] bf16 (rows 8-15 zero).
// ---------------------------------------------------------------------------
__global__ void __launch_bounds__(256, 1)
lstm_mfma(const bf16* __restrict__ wl, const float* __restrict__ xpre0,
          const float* __restrict__ b0a, const float* __restrict__ b0b,
          const float* __restrict__ b1a, const float* __restrict__ b1b,
          bf16* __restrict__ h0seq, bf16* __restrict__ h1seq,
          float* __restrict__ aseq, unsigned* __restrict__ ctr)
{
  __shared__ float gbuf[4][16][8];
  const int tid = threadIdx.x;
  const int l = tid & 63, w = tid >> 6;            // w = gate 0..3
  const int layer = blockIdx.x >> 4, U = (blockIdx.x & 15) * 16;
  const int row = w * 256 + U + (l & 15);          // gate-row in [0,1024)
  const int ko = (l >> 4) * 8;                     // k offset within 32-chunk
  const bf16* whh = wl + (size_t)(layer ? 3 : 1) * 262144 + (size_t)row * 256;
  const bf16* wih1 = wl + (size_t)2 * 262144 + (size_t)row * 256;
  bf16x8 bw[8], bx[8];
  #pragma unroll
  for (int kt = 0; kt < 8; ++kt) bw[kt] = *(const bf16x8*)(whh + kt * 32 + ko);
  if (layer) {
    #pragma unroll
    for (int kt = 0; kt < 8; ++kt) bx[kt] = *(const bf16x8*)(wih1 + kt * 32 + ko);
  }
  const float bsum = layer ? (b1a[row] + b1b[row]) : (b0a[row] + b0b[row]);
  bf16* hs = layer ? h1seq : h0seq;
  unsigned* c0 = ctr;
  unsigned* c1 = ctr + 128;
  unsigned* cs = layer ? c1 : c0;
  float cstate = 0.f;
  const int au = tid >> 3, ab = tid & 7;           // activation (unit, batch)

  for (int t = 0; t < 128; ++t) {
    // prefetch xpre (layer0) before the wait — independent of h
    float xp[4] = {0.f, 0.f, 0.f, 0.f};
    if (!layer && (l >> 4) < 2) {
      #pragma unroll
      for (int r = 0; r < 4; ++r) {
        int bb = (l >> 4) * 4 + r;
        xp[r] = xpre0[((size_t)((bb << 7) | t)) * 1024 + row];
      }
    }
    if (tid == 0) {
      if (layer == 0) {
        if (t > 0)
          while (__hip_atomic_load(c0 + t - 1, __ATOMIC_ACQUIRE, __HIP_MEMORY_SCOPE_AGENT) < 16u)
            __builtin_amdgcn_s_sleep(2);
      } else {
        while (__hip_atomic_load(c0 + t, __ATOMIC_ACQUIRE, __HIP_MEMORY_SCOPE_AGENT) < 16u)
          __builtin_amdgcn_s_sleep(2);
        if (t > 0)
          while (__hip_atomic_load(c1 + t - 1, __ATOMIC_ACQUIRE, __HIP_MEMORY_SCOPE_AGENT) < 16u)
            __builtin_amdgcn_s_sleep(2);
      }
    }
    __syncthreads();
    floatx4 acc; acc[0] = acc[1] = acc[2] = acc[3] = 0.f;
    if (t > 0) {
      const bf16* hp = hs + (size_t)(t - 1) * 4096 + (size_t)(l & 15) * 256 + ko;
      #pragma unroll
      for (int kt = 0; kt < 8; ++kt)
        acc = MFMA16(*(const bf16x8*)(hp + kt * 32), bw[kt], acc);
    }
    if (layer) {
      const bf16* hp = h0seq + (size_t)t * 4096 + (size_t)(l & 15) * 256 + ko;
      #pragma unroll
      for (int kt = 0; kt < 8; ++kt)
        acc = MFMA16(*(const bf16x8*)(hp + kt * 32), bx[kt], acc);
    }
    if ((l >> 4) < 2) {
      #pragma unroll
      for (int r = 0; r < 4; ++r) {
        int bb = (l >> 4) * 4 + r;
        gbuf[w][l & 15][bb] = acc[r] + bsum + xp[r];
      }
    }
    __syncthreads();
    if (tid < 128) {
      float gi = gbuf[0][au][ab], gf = gbuf[1][au][ab];
      float gg = gbuf[2][au][ab], go = gbuf[3][au][ab];
      cstate = sigmf_(gf) * cstate + sigmf_(gi) * tanhf(gg);
      float h = sigmf_(go) * tanhf(cstate);
      hs[(size_t)t * 4096 + (size_t)ab * 256 + U + au] = (bf16)h;
      if (layer) aseq[((size_t)((ab << 7) | t)) * 256 + U + au] = h;
    }
    __syncthreads();
    if (tid == 0) {
      __threadfence();
      __hip_atomic_fetch_add(cs + t, 1u, __ATOMIC_RELEASE, __HIP_MEMORY_SCOPE_AGENT);
    }
  }
}

// ---------------------------------------------------------------------------
// Attention core per (b,h): scores->softmax->ctx (fp32, logits tiny).
// ---------------------------------------------------------------------------
__global__ void __launch_bounds__(256, 2)
attn_kernel(const float* __restrict__ qkv, float* __restrict__ ctxo)
{
  __shared__ float Kb[128][40];
  __shared__ float Vb[128][40];
  const int tid = threadIdx.x;
  const int b = blockIdx.x >> 3, h = blockIdx.x & 7;
  const int s = tid >> 1, half = tid & 1;
  {
    const float* kr = qkv + ((size_t)(b * 128 + s)) * 768 + 256 + h * 32 + half * 16;
    #pragma unroll
    for (int i = 0; i < 4; ++i) {
      *(float4*)&Kb[s][half * 16 + i * 4] = *(const float4*)(kr + i * 4);
      *(float4*)&Vb[s][half * 16 + i * 4] = *(const float4*)(kr + 256 + i * 4);
    }
  }
  float q[32];
  {
    const float* qr = qkv + ((size_t)(b * 128 + s)) * 768 + h * 32;
    #pragma unroll
    for (int i = 0; i < 8; ++i) {
      float4 v = *(const float4*)(qr + i * 4);
      q[i * 4 + 0] = v.x; q[i * 4 + 1] = v.y; q[i * 4 + 2] = v.z; q[i * 4 + 3] = v.w;
    }
  }
  __syncthreads();
  const float scale = 0.17677669529663687f;
  float se = 0.f;
  float ca[32];
  #pragma unroll
  for (int i = 0; i < 32; ++i) ca[i] = 0.f;
  for (int c0 = 0; c0 < 64; ++c0) {
    int c = half * 64 + c0;
    float d = 0.f;
    #pragma unroll
    for (int i = 0; i < 32; ++i) d += q[i] * Kb[c][i];
    float e = expf(d * scale);
    se += e;
    #pragma unroll
    for (int i = 0; i < 32; ++i) ca[i] += e * Vb[c][i];
  }
  se += __shfl_xor(se, 1, 64);
  #pragma unroll
  for (int i = 0; i < 32; ++i) ca[i] += __shfl_xor(ca[i], 1, 64);
  if (half == 0) {
    float inv = 1.f / se;
    float* outp = ctxo + ((size_t)(b * 128 + s)) * 256 + h * 32;
    #pragma unroll
    for (int i = 0; i < 32; i += 4) {
      float4 v; v.x = ca[i] * inv; v.y = ca[i + 1] * inv; v.z = ca[i + 2] * inv; v.w = ca[i + 3] * inv;
      *(float4*)(outp + i) = v;
    }
  }
}

// LN over 256 cols; optional fp32 mirror (final layer -> d_out 'a')
__global__ void __launch_bounds__(256, 4)
ln_kernel(const float* __restrict__ in, const float* __restrict__ g,
          const float* __restrict__ bta, float* __restrict__ out,
          float* __restrict__ mirror)
{
  const int tid = threadIdx.x;
  const int m = blockIdx.x * 4 + (tid >> 6);
  const int l = tid & 63;
  float4 v = *(const float4*)(in + (size_t)m * 256 + l * 4);
  float s = v.x + v.y + v.z + v.w;
  float s2 = v.x * v.x + v.y * v.y + v.z * v.z + v.w * v.w;
  #pragma unroll
  for (int k = 1; k < 64; k <<= 1) { s += __shfl_xor(s, k, 64); s2 += __shfl_xor(s2, k, 64); }
  float mean = s * (1.f / 256.f);
  float var = s2 * (1.f / 256.f) - mean * mean;
  float rs = rsqrtf(var + 1e-5f);
  float4 gg = *(const float4*)(g + l * 4);
  float4 bb = *(const float4*)(bta + l * 4);
  float4 o;
  o.x = (v.x - mean) * rs * gg.x + bb.x;
  o.y = (v.y - mean) * rs * gg.y + bb.y;
  o.z = (v.z - mean) * rs * gg.z + bb.z;
  o.w = (v.w - mean) * rs * gg.w + bb.w;
  *(float4*)(out + (size_t)m * 256 + l * 4) = o;
  if (mirror) *(float4*)(mirror + (size_t)m * 256 + l * 4) = o;
}

__global__ void __launch_bounds__(256)
gctx_kernel(const float* __restrict__ a, float* __restrict__ g)
{
  int b = blockIdx.x, hh = threadIdx.x;
  float s = 0.f;
  for (int ss = 0; ss < 128; ++ss) s += a[((size_t)b * 128 + ss) * 256 + hh];
  g[b * 256 + hh] = s * (1.f / 128.f);
}

__global__ void __launch_bounds__(256, 1)
head_kernel(const float* __restrict__ g, const float* __restrict__ w1,
            const float* __restrict__ b1, const float* __restrict__ w2,
            const float* __restrict__ b2, const float* __restrict__ qw,
            const float* __restrict__ qb, float* __restrict__ dout)
{
  __shared__ float hid[8][128];
  const int tid = threadIdx.x;
  for (int o = tid; o < 1024; o += 256) {
    int b = o >> 7, j = o & 127;
    float s = b1[j];
    for (int k = 0; k < 256; ++k) s += g[b * 256 + k] * w1[(size_t)k * 128 + j];
    hid[b][j] = s > 0.f ? s : 0.f;
  }
  __syncthreads();
  if (tid < 192) {
    int b = tid / 24, j = tid - b * 24;
    float s = b2[j];
    for (int k = 0; k < 128; ++k) s += hid[b][k] * w2[(size_t)k * 24 + j];
    dout[b * 24 + j] = s;
  }
  for (int o = tid; o < 576; o += 256) {
    int qi = o / 192, rr = o - qi * 192, b = rr / 24, j = rr - b * 24;
    float s = qb[qi * 24 + j];
    for (int k = 0; k < 256; ++k) s += g[b * 256 + k] * qw[((size_t)qi * 256 + k) * 24 + j];
    dout[192 + o] = s;
  }
}

// ---------------------------------------------------------------------------
extern "C" void kernel_launch(void* const* d_in, const int* in_sizes, int n_in,
                              void* d_out, int out_size, void* d_ws, size_t ws_size,
                              hipStream_t stream)
{
  (void)in_sizes; (void)n_in; (void)out_size;
  auto F = [&](int i) { return (const float*)d_in[i]; };
  char* ws = (char*)d_ws;
  size_t o = 0;
  auto alloc = [&](size_t b) { size_t r = o; o = (o + b + 255) & ~(size_t)255; return r; };

  size_t h_o    = alloc((size_t)1024 * 256 * 4);
  size_t h2_o   = alloc((size_t)1024 * 256 * 4);
  size_t go_o   = alloc((size_t)1024 * 256 * 4);
  size_t skip_o = alloc((size_t)1024 * 128 * 4);
  size_t feat_o = alloc((size_t)1024 * 256 * 4);
  size_t xpre_o = alloc((size_t)1024 * 1024 * 4);
  size_t qkv_o  = alloc((size_t)1024 * 768 * 4);
  size_t ctx_o  = alloc((size_t)1024 * 256 * 4);
  size_t pre_o  = alloc((size_t)1024 * 256 * 4);
  size_t aA_o   = alloc((size_t)1024 * 256 * 4);
  size_t aB_o   = alloc((size_t)1024 * 256 * 4);
  size_t gctx_o = alloc(8 * 256 * 4);
  size_t wl_o   = alloc((size_t)4 * 262144 * 2);          // lstm weights bf16
  size_t z_o    = alloc((size_t)2 * 1048576 + 1024);      // h0seq,h1seq bf16 + ctr
  size_t aseq_o = alloc((size_t)1024 * 256 * 4);
  int FC = 32;
  while (FC > 4 && o + (size_t)FC * 1024 * 256 * 2 > ws_size) FC >>= 1;
  size_t vb_o = alloc((size_t)FC * 1024 * 256 * 2);
  if (o > ws_size) return;

  float* hp    = (float*)(ws + h_o);
  float* h2p   = (float*)(ws + h2_o);
  float* gop   = (float*)(ws + go_o);
  float* skipp = (float*)(ws + skip_o);
  float* featp = (float*)(ws + feat_o);
  float* xprep = (float*)(ws + xpre_o);
  float* qkvp  = (float*)(ws + qkv_o);
  float* ctxp  = (float*)(ws + ctx_o);
  float* prep  = (float*)(ws + pre_o);
  float* aAp   = (float*)(ws + aA_o);
  float* aBp   = (float*)(ws + aB_o);
  float* gctxp = (float*)(ws + gctx_o);
  bf16* wlp    = (bf16*)(ws + wl_o);
  bf16* h0p    = (bf16*)(ws + z_o);
  bf16* h1p    = (bf16*)(ws + z_o + 1048576);
  unsigned* ctrp = (unsigned*)(ws + z_o + 2097152);
  float* aseqp = (float*)(ws + aseq_o);
  bf16* vbp    = (bf16*)(ws + vb_o);

  // d_out is FP32: pf@0[192], q10@192, q50@384, q90@576, sw@768[131072], a@131840[262144]
  float* outp  = (float*)d_out;
  float* sw_do = outp + 768;
  float* a_do  = outp + 131840;

  // zero h-seq pad rows + barrier counters (must be re-zeroed every launch)
  hipMemsetAsync(ws + z_o, 0, 2097152 + 1024, stream);
  cvt4_kernel<<<1024, 256, 0, stream>>>(F(26), F(27), F(30), F(31), wlp);

  // ---- flattened GRN -> variable selection weights ----
  gemm_nat<2><<<dim3(2, 256), 128, 0, stream>>>(F(0), 128, F(1), 256, hp, 256, 128, F(2), nullptr, 0);
  gemm_nat<2><<<dim3(2, 256), 128, 0, stream>>>(hp, 256, F(3), 256, h2p, 256, 256, F(4), nullptr, 0);
  gemm_nat<1><<<dim3(1, 256), 128, 0, stream>>>(h2p, 256, F(7), 128, gop, 256, 256, F(8), nullptr, 0);
  gemm_nat<1><<<dim3(1, 256), 128, 0, stream>>>(h2p, 256, F(5), 128, gop + 128, 256, 256, F(6), nullptr, 0);
  gemm_nat<1><<<dim3(1, 256), 128, 0, stream>>>(F(0), 128, F(9), 128, skipp, 128, 128, F(10), nullptr, 0);
  grnflat_sw_kernel<<<256, 256, 0, stream>>>(gop, skipp, F(11), F(12), sw_do);

  // ---- per-variable GRNs (chunked over features) ----
  int chunks = 128 / FC;
  for (int c = 0; c < chunks; ++c) {
    pervar_naive<<<dim3(32, FC), 256, 0, stream>>>(
        F(0), F(13), F(14), F(15), F(16), F(17), F(18), F(19), F(20), F(21), F(22),
        F(23), F(24), vbp, c * FC);
    selreduce_kernel<<<256, 256, 0, stream>>>(
        vbp, sw_do, F(25), featp, c * FC, FC,
        (c == 0 ? 1 : 0) | (c == chunks - 1 ? 2 : 0));
  }

  // ---- LSTM ----
  gemm_bt_nat<<<dim3(8, 256), 128, 0, stream>>>(featp, 256, F(26), xprep, 1024, 256);
  lstm_mfma<<<32, 256, 0, stream>>>(wlp, xprep, F(28), F(29), F(32), F(33),
                                    h0p, h1p, aseqp, ctrp);

  // ---- attention layers ----
  const float* ain = aseqp;
  float* louts[4] = {aAp, aBp, aAp, aBp};
  for (int l = 0; l < 4; ++l) {
    const float* wq = F(34) + (size_t)l * 65536;
    const float* wk = F(35) + (size_t)l * 65536;
    const float* wv = F(36) + (size_t)l * 65536;
    const float* wo = F(37) + (size_t)l * 65536;
    gemm_nat<0><<<dim3(2, 256), 128, 0, stream>>>(ain, 256, wq, 256, qkvp,       768, 256, nullptr, nullptr, 0);
    gemm_nat<0><<<dim3(2, 256), 128, 0, stream>>>(ain, 256, wk, 256, qkvp + 256, 768, 256, nullptr, nullptr, 0);
    gemm_nat<0><<<dim3(2, 256), 128, 0, stream>>>(ain, 256, wv, 256, qkvp + 512, 768, 256, nullptr, nullptr, 0);
    attn_kernel<<<64, 256, 0, stream>>>(qkvp, ctxp);
    gemm_nat<4><<<dim3(2, 256), 128, 0, stream>>>(ctxp, 256, wo, 256, prep, 256, 256,
                                                  F(38) + (size_t)l * 256, ain, 256);
    ln_kernel<<<256, 256, 0, stream>>>(prep, F(39) + (size_t)l * 256, F(40) + (size_t)l * 256,
                                       louts[l], l == 3 ? a_do : (float*)nullptr);
    ain = louts[l];
  }

  // ---- heads ----
  gctx_kernel<<<8, 256, 0, stream>>>(aBp, gctxp);
  head_kernel<<<1, 256, 0, stream>>>(gctxp, F(41), F(42), F(43), F(44), F(45), F(46), outp);
}

// Round 7
// 1121.372 us; speedup vs baseline: 13.0590x; 3.0336x over previous
//
#include <hip/hip_runtime.h>
#include <cstdint>
#include <cstddef>

typedef __bf16 bf16;
typedef __attribute__((ext_vector_type(4))) __bf16 bf16x4;
typedef __attribute__((ext_vector_type(8))) __bf16 bf16x8;
typedef __attribute__((ext_vector_type(4))) float floatx4;

#define MFMA16(a,b,c) __builtin_amdgcn_mfma_f32_16x16x32_bf16(a,b,c,0,0,0)

__device__ __forceinline__ float sigmf_(float x){ return 1.f/(1.f+expf(-x)); }
__device__ __forceinline__ float eluf_(float x){ return x>0.f ? x : (expf(x)-1.f); }

// ---------------------------------------------------------------------------
// MFMA GEMM: C[M,N] = epi(A[M,K] @ B^T[N,K]) ; A fp32 (cvt->bf16), BT bf16.
// Block 256 thr, tile 128x64, BK=64, swizzled LDS (byte ^= (row&7)<<4).
// EPI: 0 none, 1 +bias, 2 elu(+bias), 3 +bias2(split@128), 4 +bias+resid
// ---------------------------------------------------------------------------
template<int EPI>
__global__ void __launch_bounds__(256, 2)
gemm_bf16(const float* __restrict__ A, int lda,
          const bf16* __restrict__ BT, int ldb,
          float* __restrict__ C, int ldc,
          const float* __restrict__ b1, const float* __restrict__ b2r,
          int K)
{
  __shared__ char sm[16384 + 8192];
  const int tid = threadIdx.x;
  const int bm = blockIdx.y * 128, bn = blockIdx.x * 64;
  const int l = tid & 63, w = tid >> 6;
  const int wm = (w >> 1) * 64, wn = (w & 1) * 32;
  floatx4 acc[4][2];
  #pragma unroll
  for (int i = 0; i < 4; ++i)
    #pragma unroll
    for (int j = 0; j < 2; ++j)
      #pragma unroll
      for (int r = 0; r < 4; ++r) acc[i][j][r] = 0.f;

  for (int k0 = 0; k0 < K; k0 += 64) {
    {
      int r0 = tid >> 4, kq = (tid & 15) * 4;
      #pragma unroll
      for (int p = 0; p < 8; ++p) {
        int m = r0 + p * 16;
        float4 v = *(const float4*)(A + (size_t)(bm + m) * lda + k0 + kq);
        bf16x4 hv; hv[0]=(bf16)v.x; hv[1]=(bf16)v.y; hv[2]=(bf16)v.z; hv[3]=(bf16)v.w;
        unsigned off = ((unsigned)(m * 128 + kq * 2)) ^ ((unsigned)(m & 7) << 4);
        *(bf16x4*)(sm + off) = hv;
      }
      int n = tid >> 2, c = (tid & 3) * 16;
      const bf16* src = BT + (size_t)(bn + n) * ldb + k0 + c;
      bf16x8 v0 = *(const bf16x8*)(src);
      bf16x8 v1 = *(const bf16x8*)(src + 8);
      unsigned o0 = 16384u + (((unsigned)(n * 128 + c * 2))      ^ ((unsigned)(n & 7) << 4));
      unsigned o1 = 16384u + (((unsigned)(n * 128 + c * 2 + 16)) ^ ((unsigned)(n & 7) << 4));
      *(bf16x8*)(sm + o0) = v0;
      *(bf16x8*)(sm + o1) = v1;
    }
    __syncthreads();
    const int row = l & 15, kb = (l >> 4) * 8;
    #pragma unroll
    for (int kk = 0; kk < 64; kk += 32) {
      bf16x8 a[4], b[2];
      #pragma unroll
      for (int i = 0; i < 4; ++i) {
        int m = wm + i * 16 + row;
        unsigned off = ((unsigned)(m * 128 + (kk + kb) * 2)) ^ ((unsigned)(m & 7) << 4);
        a[i] = *(const bf16x8*)(sm + off);
      }
      #pragma unroll
      for (int j = 0; j < 2; ++j) {
        int n = wn + j * 16 + row;
        unsigned off = 16384u + (((unsigned)(n * 128 + (kk + kb) * 2)) ^ ((unsigned)(n & 7) << 4));
        b[j] = *(const bf16x8*)(sm + off);
      }
      #pragma unroll
      for (int i = 0; i < 4; ++i)
        #pragma unroll
        for (int j = 0; j < 2; ++j)
          acc[i][j] = MFMA16(a[i], b[j], acc[i][j]);
    }
    __syncthreads();
  }
  #pragma unroll
  for (int i = 0; i < 4; ++i)
    #pragma unroll
    for (int j = 0; j < 2; ++j)
      #pragma unroll
      for (int r = 0; r < 4; ++r) {
        int grow = bm + wm + i * 16 + ((l >> 4) << 2) + r;
        int gcol = bn + wn + j * 16 + (l & 15);
        float v = acc[i][j][r];
        if (EPI == 1) v += b1[gcol];
        else if (EPI == 2) { v += b1[gcol]; v = eluf_(v); }
        else if (EPI == 3) { v += (gcol < 128) ? b1[gcol] : b2r[gcol - 128]; }
        else if (EPI == 4) { v += b1[gcol] + b2r[(size_t)grow * ldc + gcol]; }
        C[(size_t)grow * ldc + gcol] = v;
      }
}

// ---------------------------------------------------------------------------
// 64x64 transpose+cvt tile helper (fp32 src -> bf16 dst, dst = src^T)
// ---------------------------------------------------------------------------
__device__ __forceinline__ void tile_tr64(const float* __restrict__ src, int srcld,
                                          bf16* __restrict__ dst, int dstld,
                                          float (*ld)[72])
{
  const int tid = threadIdx.x;
  const int r = tid >> 2, q = tid & 3;
  #pragma unroll
  for (int i = 0; i < 4; ++i) {
    int col = q * 16 + i * 4;
    *(float4*)&ld[r][col] = *(const float4*)(src + (size_t)r * srcld + col);
  }
  __syncthreads();
  bf16x8 o0, o1;
  #pragma unroll
  for (int i = 0; i < 8; ++i) o0[i] = (bf16)ld[q * 16 + i][r];
  #pragma unroll
  for (int i = 0; i < 8; ++i) o1[i] = (bf16)ld[q * 16 + 8 + i][r];
  *(bf16x8*)(dst + (size_t)r * dstld + q * 16) = o0;
  *(bf16x8*)(dst + (size_t)r * dstld + q * 16 + 8) = o1;
}

__global__ void __launch_bounds__(256)
transpose_sv(const float* __restrict__ w2, const float* __restrict__ wo,
             const float* __restrict__ wg, bf16* __restrict__ svT)
{
  __shared__ float ld[64][72];
  int mat = blockIdx.y >> 7;
  int f = blockIdx.y & 127;
  const float* src = (mat == 0 ? w2 : (mat == 1 ? wo : wg)) + (size_t)f * 65536;
  bf16* dst = svT + (size_t)blockIdx.y * 65536;
  int tc = blockIdx.x & 3, tr = blockIdx.x >> 2;
  tile_tr64(src + (size_t)(tr * 64) * 256 + tc * 64, 256,
            dst + (size_t)(tc * 64) * 256 + tr * 64, 256, ld);
}

struct TJob { const float* src; bf16* dst; int R; int C; };
struct TJobs { TJob j[22]; };

__global__ void __launch_bounds__(256)
transpose_misc(TJobs jobs)
{
  __shared__ float ld[64][72];
  TJob J = jobs.j[blockIdx.y];
  int ntc = J.C >> 6;
  int tiles = (J.R >> 6) * ntc;
  if ((int)blockIdx.x >= tiles) return;
  int tc = blockIdx.x % ntc, tr = blockIdx.x / ntc;
  tile_tr64(J.src + (size_t)(tr * 64) * J.C + tc * 64, J.C,
            J.dst + (size_t)(tc * 64) * J.R + tr * 64, J.R, ld);
}

// fp32 -> bf16 convert of 4 lstm weight matrices (each 262144 elems)
__global__ void __launch_bounds__(256)
cvt4_kernel(const float* __restrict__ s0, const float* __restrict__ s1,
            const float* __restrict__ s2, const float* __restrict__ s3,
            bf16* __restrict__ dst)
{
  size_t i = ((size_t)blockIdx.x * 256 + threadIdx.x) * 4;
  int mat = (int)(i >> 18);
  const float* s = (mat == 0) ? s0 : (mat == 1) ? s1 : (mat == 2) ? s2 : s3;
  float4 v = *(const float4*)(s + (i & 262143));
  bf16x4 o; o[0]=(bf16)v.x; o[1]=(bf16)v.y; o[2]=(bf16)v.z; o[3]=(bf16)v.w;
  *(bf16x4*)(dst + i) = o;
}

// ---------------------------------------------------------------------------
// GRN-flat combine: pre = sigmoid(g)*o + skip ; LN(128) ; softmax(128)
// ---------------------------------------------------------------------------
__global__ void __launch_bounds__(256, 4)
grnflat_sw_kernel(const float* __restrict__ go, const float* __restrict__ skip,
                  const float* __restrict__ lng, const float* __restrict__ lnb,
                  float* __restrict__ sw_out)
{
  const int tid = threadIdx.x;
  const int m = blockIdx.x * 4 + (tid >> 6);
  const int l = tid & 63, c = l * 2;
  float g0 = go[(size_t)m * 256 + c],       g1 = go[(size_t)m * 256 + c + 1];
  float o0 = go[(size_t)m * 256 + 128 + c], o1 = go[(size_t)m * 256 + 128 + c + 1];
  float sk0 = skip[(size_t)m * 128 + c],    sk1 = skip[(size_t)m * 128 + c + 1];
  float p0 = sigmf_(g0) * o0 + sk0;
  float p1 = sigmf_(g1) * o1 + sk1;
  float s = p0 + p1, s2 = p0 * p0 + p1 * p1;
  #pragma unroll
  for (int k = 1; k < 64; k <<= 1) { s += __shfl_xor(s, k, 64); s2 += __shfl_xor(s2, k, 64); }
  float mean = s * (1.f / 128.f);
  float var = s2 * (1.f / 128.f) - mean * mean;
  float rs = rsqrtf(var + 1e-5f);
  float t0 = (p0 - mean) * rs * lng[c] + lnb[c];
  float t1 = (p1 - mean) * rs * lng[c + 1] + lnb[c + 1];
  float mx = fmaxf(t0, t1);
  #pragma unroll
  for (int k = 1; k < 64; k <<= 1) mx = fmaxf(mx, __shfl_xor(mx, k, 64));
  float e0 = expf(t0 - mx), e1 = expf(t1 - mx);
  float se = e0 + e1;
  #pragma unroll
  for (int k = 1; k < 64; k <<= 1) se += __shfl_xor(se, k, 64);
  float inv = 1.f / se;
  float2 wv; wv.x = e0 * inv; wv.y = e1 * inv;
  *(float2*)(sw_out + (size_t)m * 128 + c) = wv;
}

// ---------------------------------------------------------------------------
// Per-variable GRN (MFMA): block = (feature f, 64-token tile). 512 thr, 8 waves.
// STATIC LDS 64KB: Abuf[64][256]bf16 @0 (32KB), Bbuf[256][64]bf16 @32768 (32KB).
// ---------------------------------------------------------------------------
__global__ void __launch_bounds__(512, 2)
pervar_kernel(const bf16* __restrict__ xT, const bf16* __restrict__ svT,
              const float* __restrict__ w1g, const float* __restrict__ b1g,
              const float* __restrict__ b2g, const float* __restrict__ bog,
              const float* __restrict__ bgg, const float* __restrict__ swg,
              const float* __restrict__ sbg, const float* __restrict__ lngg,
              const float* __restrict__ lnbg,
              bf16* __restrict__ vbuf, int f0)
{
  __shared__ char sm[65536];
  const int tid = threadIdx.x;
  const int fl = blockIdx.y, f = f0 + fl, tile = blockIdx.x;   // tile 0..15
  const int l = tid & 63, w = tid >> 6;
  const int wm = (w >> 2) * 32, wn = (w & 3) * 64;
  const int row = l & 15, kb = (l >> 4) * 8;
  const size_t fb = (size_t)f * 256;

  // ---- h1 = elu(x*w1 + b1) -> Abuf ----
  {
    int m = tid >> 3, ks8 = (tid & 7) * 32;
    float x = (float)xT[(size_t)f * 1024 + tile * 64 + m];
    #pragma unroll
    for (int i = 0; i < 4; ++i) {
      int k = ks8 + i * 8;
      float4 w0v = *(const float4*)(w1g + fb + k);
      float4 w1v = *(const float4*)(w1g + fb + k + 4);
      float4 b0v = *(const float4*)(b1g + fb + k);
      float4 b1v = *(const float4*)(b1g + fb + k + 4);
      bf16x8 hv;
      hv[0] = (bf16)eluf_(x * w0v.x + b0v.x);
      hv[1] = (bf16)eluf_(x * w0v.y + b0v.y);
      hv[2] = (bf16)eluf_(x * w0v.z + b0v.z);
      hv[3] = (bf16)eluf_(x * w0v.w + b0v.w);
      hv[4] = (bf16)eluf_(x * w1v.x + b1v.x);
      hv[5] = (bf16)eluf_(x * w1v.y + b1v.y);
      hv[6] = (bf16)eluf_(x * w1v.z + b1v.z);
      hv[7] = (bf16)eluf_(x * w1v.w + b1v.w);
      unsigned off = ((unsigned)(m * 512 + k * 2)) ^ ((unsigned)(m & 7) << 4);
      *(bf16x8*)(sm + off) = hv;
    }
  }

  auto stageB = [&](const bf16* BT, int ks) {
    int n = tid >> 1, c = (tid & 1) * 32;
    const bf16* src = BT + (size_t)n * 256 + ks * 64 + c;
    #pragma unroll
    for (int qq = 0; qq < 4; ++qq) {
      unsigned ro = (((unsigned)(n * 128 + (c + qq * 8) * 2)) ^ ((unsigned)(n & 7) << 4));
      *(bf16x8*)(sm + 32768 + ro) = *(const bf16x8*)(src + qq * 8);
    }
  };

  // ---- GEMM1: h2 = elu(h1 @ w2 + b2) ----
  floatx4 acc1[2][4];
  #pragma unroll
  for (int i = 0; i < 2; ++i)
    #pragma unroll
    for (int j = 0; j < 4; ++j)
      #pragma unroll
      for (int r = 0; r < 4; ++r) acc1[i][j][r] = 0.f;
  const bf16* w2T = svT + (size_t)f * 65536;
  for (int ks = 0; ks < 4; ++ks) {
    __syncthreads();
    stageB(w2T, ks);
    __syncthreads();
    #pragma unroll
    for (int kk = 0; kk < 64; kk += 32) {
      int kloc = kk + kb;
      bf16x8 a[2], b[4];
      #pragma unroll
      for (int i = 0; i < 2; ++i) {
        int m = wm + i * 16 + row;
        unsigned off = ((unsigned)(m * 512 + (ks * 64 + kloc) * 2)) ^ ((unsigned)(m & 7) << 4);
        a[i] = *(const bf16x8*)(sm + off);
      }
      #pragma unroll
      for (int j = 0; j < 4; ++j) {
        int n = wn + j * 16 + row;
        unsigned off = 32768u + (((unsigned)(n * 128 + kloc * 2)) ^ ((unsigned)(n & 7) << 4));
        b[j] = *(const bf16x8*)(sm + off);
      }
      #pragma unroll
      for (int i = 0; i < 2; ++i)
        #pragma unroll
        for (int j = 0; j < 4; ++j)
          acc1[i][j] = MFMA16(a[i], b[j], acc1[i][j]);
    }
  }
  __syncthreads();
  #pragma unroll
  for (int i = 0; i < 2; ++i)
    #pragma unroll
    for (int j = 0; j < 4; ++j)
      #pragma unroll
      for (int r = 0; r < 4; ++r) {
        int m = wm + i * 16 + ((l >> 4) << 2) + r;
        int col = wn + j * 16 + (l & 15);
        float v = eluf_(acc1[i][j][r] + b2g[fb + col]);
        unsigned off = ((unsigned)(m * 512 + col * 2)) ^ ((unsigned)(m & 7) << 4);
        *(bf16*)(sm + off) = (bf16)v;
      }
  __syncthreads();

  // ---- GEMM2: vo ; GEMM3: vg ----
  floatx4 accO[2][4], accG[2][4];
  #pragma unroll
  for (int i = 0; i < 2; ++i)
    #pragma unroll
    for (int j = 0; j < 4; ++j)
      #pragma unroll
      for (int r = 0; r < 4; ++r) { accO[i][j][r] = 0.f; accG[i][j][r] = 0.f; }
  const bf16* woT = svT + ((size_t)128 + f) * 65536;
  const bf16* wgT = svT + ((size_t)256 + f) * 65536;
  for (int ks = 0; ks < 4; ++ks) {
    __syncthreads();
    stageB(woT, ks);
    __syncthreads();
    #pragma unroll
    for (int kk = 0; kk < 64; kk += 32) {
      int kloc = kk + kb;
      bf16x8 a[2], b[4];
      #pragma unroll
      for (int i = 0; i < 2; ++i) {
        int m = wm + i * 16 + row;
        unsigned off = ((unsigned)(m * 512 + (ks * 64 + kloc) * 2)) ^ ((unsigned)(m & 7) << 4);
        a[i] = *(const bf16x8*)(sm + off);
      }
      #pragma unroll
      for (int j = 0; j < 4; ++j) {
        int n = wn + j * 16 + row;
        unsigned off = 32768u + (((unsigned)(n * 128 + kloc * 2)) ^ ((unsigned)(n & 7) << 4));
        b[j] = *(const bf16x8*)(sm + off);
      }
      #pragma unroll
      for (int i = 0; i < 2; ++i)
        #pragma unroll
        for (int j = 0; j < 4; ++j)
          accO[i][j] = MFMA16(a[i], b[j], accO[i][j]);
    }
  }
  for (int ks = 0; ks < 4; ++ks) {
    __syncthreads();
    stageB(wgT, ks);
    __syncthreads();
    #pragma unroll
    for (int kk = 0; kk < 64; kk += 32) {
      int kloc = kk + kb;
      bf16x8 a[2], b[4];
      #pragma unroll
      for (int i = 0; i < 2; ++i) {
        int m = wm + i * 16 + row;
        unsigned off = ((unsigned)(m * 512 + (ks * 64 + kloc) * 2)) ^ ((unsigned)(m & 7) << 4);
        a[i] = *(const bf16x8*)(sm + off);
      }
      #pragma unroll
      for (int j = 0; j < 4; ++j) {
        int n = wn + j * 16 + row;
        unsigned off = 32768u + (((unsigned)(n * 128 + kloc * 2)) ^ ((unsigned)(n & 7) << 4));
        b[j] = *(const bf16x8*)(sm + off);
      }
      #pragma unroll
      for (int i = 0; i < 2; ++i)
        #pragma unroll
        for (int j = 0; j < 4; ++j)
          accG[i][j] = MFMA16(a[i], b[j], accG[i][j]);
    }
  }
  __syncthreads();
  // ---- v_pre = sigmoid(vg+bg)*(vo+bo) + x*sw + sb -> Abuf (bf16) ----
  {
    float xm[2][4];
    #pragma unroll
    for (int i = 0; i < 2; ++i)
      #pragma unroll
      for (int r = 0; r < 4; ++r) {
        int m = wm + i * 16 + ((l >> 4) << 2) + r;
        xm[i][r] = (float)xT[(size_t)f * 1024 + tile * 64 + m];
      }
    #pragma unroll
    for (int i = 0; i < 2; ++i)
      #pragma unroll
      for (int j = 0; j < 4; ++j)
        #pragma unroll
        for (int r = 0; r < 4; ++r) {
          int m = wm + i * 16 + ((l >> 4) << 2) + r;
          int col = wn + j * 16 + (l & 15);
          float vg = sigmf_(accG[i][j][r] + bgg[fb + col]);
          float vo = accO[i][j][r] + bog[fb + col];
          float pre = vg * vo + xm[i][r] * swg[fb + col] + sbg[fb + col];
          unsigned off = ((unsigned)(m * 512 + col * 2)) ^ ((unsigned)(m & 7) << 4);
          *(bf16*)(sm + off) = (bf16)pre;
        }
  }
  __syncthreads();
  // ---- LN over 256 per row, write v bf16 ----
  {
    int m = tid >> 3, q = tid & 7;
    float vals[32];
    float s = 0.f, s2 = 0.f;
    #pragma unroll
    for (int i = 0; i < 4; ++i) {
      unsigned off = ((unsigned)(m * 512 + (q * 32 + i * 8) * 2)) ^ ((unsigned)(m & 7) << 4);
      bf16x8 hv = *(const bf16x8*)(sm + off);
      #pragma unroll
      for (int j = 0; j < 8; ++j) {
        float x = (float)hv[j];
        vals[i * 8 + j] = x; s += x; s2 += x * x;
      }
    }
    s += __shfl_xor(s, 1, 64);  s += __shfl_xor(s, 2, 64);  s += __shfl_xor(s, 4, 64);
    s2 += __shfl_xor(s2, 1, 64); s2 += __shfl_xor(s2, 2, 64); s2 += __shfl_xor(s2, 4, 64);
    float mean = s * (1.f / 256.f);
    float var = s2 * (1.f / 256.f) - mean * mean;
    float rs = rsqrtf(var + 1e-5f);
    bf16* dst = vbuf + ((size_t)fl * 1024 + tile * 64 + m) * 256 + q * 32;
    #pragma unroll
    for (int i = 0; i < 4; ++i) {
      int c = q * 32 + i * 8;
      float4 g0 = *(const float4*)(lngg + fb + c);
      float4 g1 = *(const float4*)(lngg + fb + c + 4);
      float4 bb0 = *(const float4*)(lnbg + fb + c);
      float4 bb1 = *(const float4*)(lnbg + fb + c + 4);
      bf16x8 ov;
      ov[0] = (bf16)((vals[i * 8 + 0] - mean) * rs * g0.x + bb0.x);
      ov[1] = (bf16)((vals[i * 8 + 1] - mean) * rs * g0.y + bb0.y);
      ov[2] = (bf16)((vals[i * 8 + 2] - mean) * rs * g0.z + bb0.z);
      ov[3] = (bf16)((vals[i * 8 + 3] - mean) * rs * g0.w + bb0.w);
      ov[4] = (bf16)((vals[i * 8 + 4] - mean) * rs * g1.x + bb1.x);
      ov[5] = (bf16)((vals[i * 8 + 5] - mean) * rs * g1.y + bb1.y);
      ov[6] = (bf16)((vals[i * 8 + 6] - mean) * rs * g1.z + bb1.z);
      ov[7] = (bf16)((vals[i * 8 + 7] - mean) * rs * g1.w + bb1.w);
      *(bf16x8*)(dst + i * 8) = ov;
    }
  }
}

// ---------------------------------------------------------------------------
// sel reduce: feats[m][h] (+=) sum_f v[f][m][h]*sw[m][f] (+pos_enc at end)
// ---------------------------------------------------------------------------
__global__ void __launch_bounds__(256, 4)
selreduce_kernel(const bf16* __restrict__ vbuf, const float* __restrict__ sw,
                 const float* __restrict__ pos, float* __restrict__ feats,
                 int f0, int FC, int flags)
{
  const int tid = threadIdx.x;
  const int m = blockIdx.x * 4 + (tid >> 6);
  const int hh = (tid & 63) * 4;
  float a0, a1, a2, a3;
  if (flags & 1) { a0 = a1 = a2 = a3 = 0.f; }
  else {
    float4 v = *(const float4*)(feats + (size_t)m * 256 + hh);
    a0 = v.x; a1 = v.y; a2 = v.z; a3 = v.w;
  }
  for (int fi = 0; fi < FC; ++fi) {
    float wgt = sw[(size_t)m * 128 + f0 + fi];
    bf16x4 v = *(const bf16x4*)(vbuf + ((size_t)fi * 1024 + m) * 256 + hh);
    a0 += wgt * (float)v[0]; a1 += wgt * (float)v[1];
    a2 += wgt * (float)v[2]; a3 += wgt * (float)v[3];
  }
  if (flags & 2) {
    float4 p = *(const float4*)(pos + (size_t)(m & 127) * 256 + hh);
    a0 += p.x; a1 += p.y; a2 += p.z; a3 += p.w;
  }
  float4 o; o.x = a0; o.y = a1; o.z = a2; o.w = a3;
  *(float4*)(feats + (size_t)m * 256 + hh) = o;
}

// ---------------------------------------------------------------------------
// LSTM: 32 blocks x 256 thr (unchanged from round 6; 573us, works)
// ---------------------------------------------------------------------------
__global__ void __launch_bounds__(256, 1)
lstm_mfma(const bf16* __restrict__ wl, const float* __restrict__ xpre0,
          const float* __restrict__ b0a, const float* __restrict__ b0b,
          const float* __restrict__ b1a, const float* __restrict__ b1b,
          bf16* __restrict__ h0seq, bf16* __restrict__ h1seq,
          float* __restrict__ aseq, unsigned* __restrict__ ctr)
{
  __shared__ float gbuf[4][16][8];
  const int tid = threadIdx.x;
  const int l = tid & 63, w = tid >> 6;
  const int layer = blockIdx.x >> 4, U = (blockIdx.x & 15) * 16;
  const int row = w * 256 + U + (l & 15);
  const int ko = (l >> 4) * 8;
  const bf16* whh = wl + (size_t)(layer ? 3 : 1) * 262144 + (size_t)row * 256;
  const bf16* wih1 = wl + (size_t)2 * 262144 + (size_t)row * 256;
  bf16x8 bw[8], bx[8];
  #pragma unroll
  for (int kt = 0; kt < 8; ++kt) bw[kt] = *(const bf16x8*)(whh + kt * 32 + ko);
  if (layer) {
    #pragma unroll
    for (int kt = 0; kt < 8; ++kt) bx[kt] = *(const bf16x8*)(wih1 + kt * 32 + ko);
  }
  const float bsum = layer ? (b1a[row] + b1b[row]) : (b0a[row] + b0b[row]);
  bf16* hs = layer ? h1seq : h0seq;
  unsigned* c0 = ctr;
  unsigned* c1 = ctr + 128;
  unsigned* cs = layer ? c1 : c0;
  float cstate = 0.f;
  const int au = tid >> 3, ab = tid & 7;

  for (int t = 0; t < 128; ++t) {
    float xp[4] = {0.f, 0.f, 0.f, 0.f};
    if (!layer && (l >> 4) < 2) {
      #pragma unroll
      for (int r = 0; r < 4; ++r) {
        int bb = (l >> 4) * 4 + r;
        xp[r] = xpre0[((size_t)((bb << 7) | t)) * 1024 + row];
      }
    }
    if (tid == 0) {
      if (layer == 0) {
        if (t > 0)
          while (__hip_atomic_load(c0 + t - 1, __ATOMIC_ACQUIRE, __HIP_MEMORY_SCOPE_AGENT) < 16u)
            __builtin_amdgcn_s_sleep(2);
      } else {
        while (__hip_atomic_load(c0 + t, __ATOMIC_ACQUIRE, __HIP_MEMORY_SCOPE_AGENT) < 16u)
          __builtin_amdgcn_s_sleep(2);
        if (t > 0)
          while (__hip_atomic_load(c1 + t - 1, __ATOMIC_ACQUIRE, __HIP_MEMORY_SCOPE_AGENT) < 16u)
            __builtin_amdgcn_s_sleep(2);
      }
    }
    __syncthreads();
    floatx4 acc; acc[0] = acc[1] = acc[2] = acc[3] = 0.f;
    if (t > 0) {
      const bf16* hp = hs + (size_t)(t - 1) * 4096 + (size_t)(l & 15) * 256 + ko;
      #pragma unroll
      for (int kt = 0; kt < 8; ++kt)
        acc = MFMA16(*(const bf16x8*)(hp + kt * 32), bw[kt], acc);
    }
    if (layer) {
      const bf16* hp = h0seq + (size_t)t * 4096 + (size_t)(l & 15) * 256 + ko;
      #pragma unroll
      for (int kt = 0; kt < 8; ++kt)
        acc = MFMA16(*(const bf16x8*)(hp + kt * 32), bx[kt], acc);
    }
    if ((l >> 4) < 2) {
      #pragma unroll
      for (int r = 0; r < 4; ++r) {
        int bb = (l >> 4) * 4 + r;
        gbuf[w][l & 15][bb] = acc[r] + bsum + xp[r];
      }
    }
    __syncthreads();
    if (tid < 128) {
      float gi = gbuf[0][au][ab], gf = gbuf[1][au][ab];
      float gg = gbuf[2][au][ab], go = gbuf[3][au][ab];
      cstate = sigmf_(gf) * cstate + sigmf_(gi) * tanhf(gg);
      float h = sigmf_(go) * tanhf(cstate);
      hs[(size_t)t * 4096 + (size_t)ab * 256 + U + au] = (bf16)h;
      if (layer) aseq[((size_t)((ab << 7) | t)) * 256 + U + au] = h;
    }
    __syncthreads();
    if (tid == 0) {
      __threadfence();
      __hip_atomic_fetch_add(cs + t, 1u, __ATOMIC_RELEASE, __HIP_MEMORY_SCOPE_AGENT);
    }
  }
}

// ---------------------------------------------------------------------------
// Attention core per (b,h): scores->softmax->ctx (fp32, logits tiny).
// ---------------------------------------------------------------------------
__global__ void __launch_bounds__(256, 2)
attn_kernel(const float* __restrict__ qkv, float* __restrict__ ctxo)
{
  __shared__ float Kb[128][40];
  __shared__ float Vb[128][40];
  const int tid = threadIdx.x;
  const int b = blockIdx.x >> 3, h = blockIdx.x & 7;
  const int s = tid >> 1, half = tid & 1;
  {
    const float* kr = qkv + ((size_t)(b * 128 + s)) * 768 + 256 + h * 32 + half * 16;
    #pragma unroll
    for (int i = 0; i < 4; ++i) {
      *(float4*)&Kb[s][half * 16 + i * 4] = *(const float4*)(kr + i * 4);
      *(float4*)&Vb[s][half * 16 + i * 4] = *(const float4*)(kr + 256 + i * 4);
    }
  }
  float q[32];
  {
    const float* qr = qkv + ((size_t)(b * 128 + s)) * 768 + h * 32;
    #pragma unroll
    for (int i = 0; i < 8; ++i) {
      float4 v = *(const float4*)(qr + i * 4);
      q[i * 4 + 0] = v.x; q[i * 4 + 1] = v.y; q[i * 4 + 2] = v.z; q[i * 4 + 3] = v.w;
    }
  }
  __syncthreads();
  const float scale = 0.17677669529663687f;
  float se = 0.f;
  float ca[32];
  #pragma unroll
  for (int i = 0; i < 32; ++i) ca[i] = 0.f;
  for (int c0 = 0; c0 < 64; ++c0) {
    int c = half * 64 + c0;
    float d = 0.f;
    #pragma unroll
    for (int i = 0; i < 32; ++i) d += q[i] * Kb[c][i];
    float e = expf(d * scale);
    se += e;
    #pragma unroll
    for (int i = 0; i < 32; ++i) ca[i] += e * Vb[c][i];
  }
  se += __shfl_xor(se, 1, 64);
  #pragma unroll
  for (int i = 0; i < 32; ++i) ca[i] += __shfl_xor(ca[i], 1, 64);
  if (half == 0) {
    float inv = 1.f / se;
    float* outp = ctxo + ((size_t)(b * 128 + s)) * 256 + h * 32;
    #pragma unroll
    for (int i = 0; i < 32; i += 4) {
      float4 v; v.x = ca[i] * inv; v.y = ca[i + 1] * inv; v.z = ca[i + 2] * inv; v.w = ca[i + 3] * inv;
      *(float4*)(outp + i) = v;
    }
  }
}

// LN over 256 cols; optional fp32 mirror (final layer -> d_out 'a')
__global__ void __launch_bounds__(256, 4)
ln_kernel(const float* __restrict__ in, const float* __restrict__ g,
          const float* __restrict__ bta, float* __restrict__ out,
          float* __restrict__ mirror)
{
  const int tid = threadIdx.x;
  const int m = blockIdx.x * 4 + (tid >> 6);
  const int l = tid & 63;
  float4 v = *(const float4*)(in + (size_t)m * 256 + l * 4);
  float s = v.x + v.y + v.z + v.w;
  float s2 = v.x * v.x + v.y * v.y + v.z * v.z + v.w * v.w;
  #pragma unroll
  for (int k = 1; k < 64; k <<= 1) { s += __shfl_xor(s, k, 64); s2 += __shfl_xor(s2, k, 64); }
  float mean = s * (1.f / 256.f);
  float var = s2 * (1.f / 256.f) - mean * mean;
  float rs = rsqrtf(var + 1e-5f);
  float4 gg = *(const float4*)(g + l * 4);
  float4 bb = *(const float4*)(bta + l * 4);
  float4 o;
  o.x = (v.x - mean) * rs * gg.x + bb.x;
  o.y = (v.y - mean) * rs * gg.y + bb.y;
  o.z = (v.z - mean) * rs * gg.z + bb.z;
  o.w = (v.w - mean) * rs * gg.w + bb.w;
  *(float4*)(out + (size_t)m * 256 + l * 4) = o;
  if (mirror) *(float4*)(mirror + (size_t)m * 256 + l * 4) = o;
}

__global__ void __launch_bounds__(256)
gctx_kernel(const float* __restrict__ a, float* __restrict__ g)
{
  int b = blockIdx.x, hh = threadIdx.x;
  float s = 0.f;
  for (int ss = 0; ss < 128; ++ss) s += a[((size_t)b * 128 + ss) * 256 + hh];
  g[b * 256 + hh] = s * (1.f / 128.f);
}

__global__ void __launch_bounds__(256, 1)
head_kernel(const float* __restrict__ g, const float* __restrict__ w1,
            const float* __restrict__ b1, const float* __restrict__ w2,
            const float* __restrict__ b2, const float* __restrict__ qw,
            const float* __restrict__ qb, float* __restrict__ dout)
{
  __shared__ float hid[8][128];
  const int tid = threadIdx.x;
  for (int o = tid; o < 1024; o += 256) {
    int b = o >> 7, j = o & 127;
    float s = b1[j];
    for (int k = 0; k < 256; ++k) s += g[b * 256 + k] * w1[(size_t)k * 128 + j];
    hid[b][j] = s > 0.f ? s : 0.f;
  }
  __syncthreads();
  if (tid < 192) {
    int b = tid / 24, j = tid - b * 24;
    float s = b2[j];
    for (int k = 0; k < 128; ++k) s += hid[b][k] * w2[(size_t)k * 24 + j];
    dout[b * 24 + j] = s;
  }
  for (int o = tid; o < 576; o += 256) {
    int qi = o / 192, rr = o - qi * 192, b = rr / 24, j = rr - b * 24;
    float s = qb[qi * 24 + j];
    for (int k = 0; k < 256; ++k) s += g[b * 256 + k] * qw[((size_t)qi * 256 + k) * 24 + j];
    dout[192 + o] = s;
  }
}

// ---------------------------------------------------------------------------
extern "C" void kernel_launch(void* const* d_in, const int* in_sizes, int n_in,
                              void* d_out, int out_size, void* d_ws, size_t ws_size,
                              hipStream_t stream)
{
  (void)in_sizes; (void)n_in; (void)out_size;
  auto F = [&](int i) { return (const float*)d_in[i]; };
  char* ws = (char*)d_ws;
  size_t o = 0;
  auto alloc = [&](size_t b) { size_t r = o; o = (o + b + 255) & ~(size_t)255; return r; };

  size_t svT_o  = alloc((size_t)3 * 128 * 65536 * 2);   // 50.3MB bf16 [3][128][256][256]
  size_t wl_o   = alloc((size_t)4 * 262144 * 2);        // lstm weights bf16
  size_t qkvT_o = alloc((size_t)4 * 196608 * 2);        // att QKV^T bf16 (fused 768xK)
  size_t woT_o  = alloc((size_t)4 * 65536 * 2);
  size_t w1T_o  = alloc(256 * 128 * 2);
  size_t w2T_o  = alloc(256 * 256 * 2);
  size_t goT_o  = alloc(256 * 256 * 2);
  size_t swT_o  = alloc(128 * 128 * 2);
  size_t xT_o   = alloc(128 * 1024 * 2);
  size_t h_o    = alloc((size_t)1024 * 256 * 4);
  size_t h2_o   = alloc((size_t)1024 * 256 * 4);
  size_t go_o   = alloc((size_t)1024 * 256 * 4);
  size_t skip_o = alloc((size_t)1024 * 128 * 4);
  size_t feat_o = alloc((size_t)1024 * 256 * 4);
  size_t xpre_o = alloc((size_t)1024 * 1024 * 4);
  size_t qkv_o  = alloc((size_t)1024 * 768 * 4);
  size_t ctx_o  = alloc((size_t)1024 * 256 * 4);
  size_t pre_o  = alloc((size_t)1024 * 256 * 4);
  size_t aA_o   = alloc((size_t)1024 * 256 * 4);
  size_t aB_o   = alloc((size_t)1024 * 256 * 4);
  size_t gctx_o = alloc(8 * 256 * 4);
  size_t z_o    = alloc((size_t)2 * 1048576 + 1024);    // h0seq,h1seq bf16 + ctr
  size_t aseq_o = alloc((size_t)1024 * 256 * 4);
  int FC = 32;
  while (FC > 4 && o + (size_t)FC * 1024 * 256 * 2 > ws_size) FC >>= 1;
  size_t vb_o = alloc((size_t)FC * 1024 * 256 * 2);
  if (o > ws_size) return;

  bf16* svTp  = (bf16*)(ws + svT_o);
  bf16* wlp   = (bf16*)(ws + wl_o);
  bf16* qkvTp = (bf16*)(ws + qkvT_o);
  bf16* woTp  = (bf16*)(ws + woT_o);
  bf16* w1Tp  = (bf16*)(ws + w1T_o);
  bf16* w2Tp  = (bf16*)(ws + w2T_o);
  bf16* goTp  = (bf16*)(ws + goT_o);
  bf16* swTp  = (bf16*)(ws + swT_o);
  bf16* xTp   = (bf16*)(ws + xT_o);
  float* hp    = (float*)(ws + h_o);
  float* h2p   = (float*)(ws + h2_o);
  float* gop   = (float*)(ws + go_o);
  float* skipp = (float*)(ws + skip_o);
  float* featp = (float*)(ws + feat_o);
  float* xprep = (float*)(ws + xpre_o);
  float* qkvp  = (float*)(ws + qkv_o);
  float* ctxp  = (float*)(ws + ctx_o);
  float* prep  = (float*)(ws + pre_o);
  float* aAp   = (float*)(ws + aA_o);
  float* aBp   = (float*)(ws + aB_o);
  float* gctxp = (float*)(ws + gctx_o);
  bf16* h0p    = (bf16*)(ws + z_o);
  bf16* h1p    = (bf16*)(ws + z_o + 1048576);
  unsigned* ctrp = (unsigned*)(ws + z_o + 2097152);
  float* aseqp = (float*)(ws + aseq_o);
  bf16* vbp    = (bf16*)(ws + vb_o);

  // d_out is FP32: pf@0[192], q10@192, q50@384, q90@576, sw@768[131072], a@131840[262144]
  float* outp  = (float*)d_out;
  float* sw_do = outp + 768;
  float* a_do  = outp + 131840;

  hipMemsetAsync(ws + z_o, 0, 2097152 + 1024, stream);

  // ---- weight prep (every launch) ----
  transpose_sv<<<dim3(16, 384), 256, 0, stream>>>(F(15), F(17), F(19), svTp);
  {
    TJobs tj; int nj = 0;
    auto addj = [&](const float* s, bf16* d, int R, int C) { tj.j[nj].src = s; tj.j[nj].dst = d; tj.j[nj].R = R; tj.j[nj].C = C; ++nj; };
    for (int l = 0; l < 4; ++l) {
      addj(F(34) + (size_t)l * 65536, qkvTp + (size_t)l * 196608, 256, 256);
      addj(F(35) + (size_t)l * 65536, qkvTp + (size_t)l * 196608 + 65536, 256, 256);
      addj(F(36) + (size_t)l * 65536, qkvTp + (size_t)l * 196608 + 131072, 256, 256);
      addj(F(37) + (size_t)l * 65536, woTp + (size_t)l * 65536, 256, 256);
    }
    addj(F(1), w1Tp, 128, 256);
    addj(F(3), w2Tp, 256, 256);
    addj(F(7), goTp, 256, 128);              // wg^T -> rows 0..127
    addj(F(5), goTp + 128 * 256, 256, 128);  // wo^T -> rows 128..255
    addj(F(9), swTp, 128, 128);
    addj(F(0), xTp, 1024, 128);
    transpose_misc<<<dim3(32, 22), 256, 0, stream>>>(tj);
  }
  cvt4_kernel<<<1024, 256, 0, stream>>>(F(26), F(27), F(30), F(31), wlp);

  auto gemm = [&](int epi, const float* A, int lda, const bf16* BT, int ldb,
                  float* C, int ldc, int M, int N, int K,
                  const float* b1, const float* b2r) {
    dim3 g(N / 64, M / 128);
    switch (epi) {
      case 0: gemm_bf16<0><<<g, 256, 0, stream>>>(A, lda, BT, ldb, C, ldc, b1, b2r, K); break;
      case 1: gemm_bf16<1><<<g, 256, 0, stream>>>(A, lda, BT, ldb, C, ldc, b1, b2r, K); break;
      case 2: gemm_bf16<2><<<g, 256, 0, stream>>>(A, lda, BT, ldb, C, ldc, b1, b2r, K); break;
      case 3: gemm_bf16<3><<<g, 256, 0, stream>>>(A, lda, BT, ldb, C, ldc, b1, b2r, K); break;
      case 4: gemm_bf16<4><<<g, 256, 0, stream>>>(A, lda, BT, ldb, C, ldc, b1, b2r, K); break;
    }
  };

  // ---- flattened GRN -> variable selection weights ----
  gemm(2, F(0), 128, w1Tp, 128, hp, 256, 1024, 256, 128, F(2), nullptr);
  gemm(2, hp, 256, w2Tp, 256, h2p, 256, 1024, 256, 256, F(4), nullptr);
  gemm(3, h2p, 256, goTp, 256, gop, 256, 1024, 256, 256, F(8), F(6));
  gemm(1, F(0), 128, swTp, 128, skipp, 128, 1024, 128, 128, F(10), nullptr);
  grnflat_sw_kernel<<<256, 256, 0, stream>>>(gop, skipp, F(11), F(12), sw_do);

  // ---- per-variable GRNs (MFMA, chunked over features) ----
  int chunks = 128 / FC;
  for (int c = 0; c < chunks; ++c) {
    pervar_kernel<<<dim3(16, FC), 512, 0, stream>>>(
        xTp, svTp, F(13), F(14), F(16), F(18), F(20), F(21), F(22), F(23), F(24),
        vbp, c * FC);
    selreduce_kernel<<<256, 256, 0, stream>>>(
        vbp, sw_do, F(25), featp, c * FC, FC,
        (c == 0 ? 1 : 0) | (c == chunks - 1 ? 2 : 0));
  }

  // ---- LSTM ----
  gemm(0, featp, 256, wlp, 256, xprep, 1024, 1024, 1024, 256, nullptr, nullptr);
  lstm_mfma<<<32, 256, 0, stream>>>(wlp, xprep, F(28), F(29), F(32), F(33),
                                    h0p, h1p, aseqp, ctrp);

  // ---- attention layers ----
  const float* ain = aseqp;
  float* louts[4] = {aAp, aBp, aAp, aBp};
  for (int l = 0; l < 4; ++l) {
    gemm(0, ain, 256, qkvTp + (size_t)l * 196608, 256, qkvp, 768, 1024, 768, 256, nullptr, nullptr);
    attn_kernel<<<64, 256, 0, stream>>>(qkvp, ctxp);
    gemm(4, ctxp, 256, woTp + (size_t)l * 65536, 256, prep, 256, 1024, 256, 256,
         F(38) + (size_t)l * 256, ain);
    ln_kernel<<<256, 256, 0, stream>>>(prep, F(39) + (size_t)l * 256, F(40) + (size_t)l * 256,
                                       louts[l], l == 3 ? a_do : (float*)nullptr);
    ain = louts[l];
  }

  // ---- heads ----
  gctx_kernel<<<8, 256, 0, stream>>>(aBp, gctxp);
  head_kernel<<<1, 256, 0, stream>>>(gctxp, F(41), F(42), F(43), F(44), F(45), F(46), outp);
}